// Round 1
// baseline (734.067 us; speedup 1.0000x reference)
//
#include <hip/hip_runtime.h>
#include <math.h>

#define PB    8
#define PIX   64
#define CH    64
#define HALF  32
#define CI    8
#define SIM   4
#define KK    49
#define LROW  65      // LDS row stride in floats (bank-conflict-free)
#define LROWS 81      // 64 rows activation + 49-32=17 extra (rows 32..80 hold wdyn)
#define EPSF  1e-5f

__device__ __forceinline__ float gelu_f(float v) {
    return 0.5f * v * (1.0f + erff(v * 0.7071067811865476f));
}
__device__ __forceinline__ float sigmoid_f(float v) {
    return 1.0f / (1.0f + expf(-v));
}

__global__ __launch_bounds__(64, 2)
void gmlp_fused(const float* __restrict__ x,
                const float* __restrict__ w_hid,   const float* __restrict__ b_hid,
                const float* __restrict__ xcnn_w1, const float* __restrict__ xcnn_b1,
                const float* __restrict__ xcnn_ln_w, const float* __restrict__ xcnn_ln_b,
                const float* __restrict__ xcnn_dw_w, const float* __restrict__ xcnn_dw_b,
                const float* __restrict__ ci_w1,   const float* __restrict__ ci_b1,
                const float* __restrict__ ci_ln_w, const float* __restrict__ ci_ln_b,
                const float* __restrict__ ci_w2,   const float* __restrict__ ci_b2,
                const float* __restrict__ si_w1,   const float* __restrict__ si_b1,
                const float* __restrict__ si_ln_w, const float* __restrict__ si_ln_b,
                const float* __restrict__ si_w2,   const float* __restrict__ si_b2,
                const float* __restrict__ proj_w,  const float* __restrict__ proj_b,
                const float* __restrict__ out_w,   const float* __restrict__ out_b,
                const float* __restrict__ sgu_ln_w, const float* __restrict__ sgu_ln_b,
                const float* __restrict__ dwb_w0,
                const float* __restrict__ idw_w1,  const float* __restrict__ idw_b1,
                const float* __restrict__ idw_bn_w, const float* __restrict__ idw_bn_b,
                const float* __restrict__ idw_w2,  const float* __restrict__ idw_b2,
                const float* __restrict__ dwb_w2,
                float* __restrict__ out)
{
    __shared__ float buf[LROWS][LROW];   // [channel-ish row][pixel]
    __shared__ float pooled_s[CH];

    const int t  = threadIdx.x;          // pixel id 0..63
    const int py = t >> 3, px = t & 7;
    const int patch = blockIdx.x;        // b*1024 + ph*32 + pw
    const int pw = patch & 31;
    const int ph = (patch >> 5) & 31;
    const int bb = patch >> 10;
    const int gy = ph * PB + py, gx = pw * PB + px;
    const int HW = 256 * 256;
    const float* xin = x + bb * CH * HW + gy * 256 + gx;

    // ---- stage input patch into LDS [c][pixel]
    #pragma unroll 8
    for (int c = 0; c < CH; ++c) buf[c][t] = xin[c * HW];
    __syncthreads();

    // ---- hidden 1x1 conv + gelu -> res (ch 0..31), gate (ch 32..63)
    float res[HALF], gate[HALF];
    #pragma unroll
    for (int o = 0; o < HALF; ++o) { res[o] = b_hid[o]; gate[o] = b_hid[o + HALF]; }
    for (int c = 0; c < CH; ++c) {
        float xv = buf[c][t];
        #pragma unroll
        for (int o = 0; o < HALF; ++o) {
            res[o]  = fmaf(w_hid[o * CH + c],          xv, res[o]);
            gate[o] = fmaf(w_hid[(o + HALF) * CH + c], xv, gate[o]);
        }
    }
    #pragma unroll
    for (int o = 0; o < HALF; ++o) { res[o] = gelu_f(res[o]); gate[o] = gelu_f(gate[o]); }
    __syncthreads();

    // ---- stage h
    #pragma unroll
    for (int o = 0; o < HALF; ++o) { buf[o][t] = res[o]; buf[o + HALF][t] = gate[o]; }
    __syncthreads();

    // ---- xcnn 1x1 conv
    float xc[CH];
    #pragma unroll
    for (int o = 0; o < CH; ++o) xc[o] = xcnn_b1[o];
    for (int c = 0; c < CH; ++c) {
        float hv = buf[c][t];
        #pragma unroll
        for (int o = 0; o < CH; ++o) xc[o] = fmaf(xcnn_w1[o * CH + c], hv, xc[o]);
    }
    // LN over 64 channels (per thread, registers)
    {
        float s = 0.f;
        #pragma unroll
        for (int o = 0; o < CH; ++o) s += xc[o];
        float mu = s * (1.0f / CH);
        float s2 = 0.f;
        #pragma unroll
        for (int o = 0; o < CH; ++o) { float d = xc[o] - mu; s2 = fmaf(d, d, s2); }
        float rstd = rsqrtf(s2 * (1.0f / CH) + EPSF);
        #pragma unroll
        for (int o = 0; o < CH; ++o)
            xc[o] = (xc[o] - mu) * rstd * xcnn_ln_w[o] + xcnn_ln_b[o];
    }
    __syncthreads();
    #pragma unroll
    for (int o = 0; o < CH; ++o) buf[o][t] = xc[o];
    __syncthreads();

    // ---- depthwise 3x3 (SAME, within patch) + bias + gelu
    int   pn3[9]; float msk3[9];
    #pragma unroll
    for (int ki = 0; ki < 3; ++ki)
        #pragma unroll
        for (int kj = 0; kj < 3; ++kj) {
            int r = py + ki - 1, cc = px + kj - 1;
            bool v = ((unsigned)r < 8u) && ((unsigned)cc < 8u);
            pn3[ki * 3 + kj] = v ? (r * 8 + cc) : 0;
            msk3[ki * 3 + kj] = v ? 1.0f : 0.0f;
        }
    float xc2[CH];
    #pragma unroll
    for (int o = 0; o < CH; ++o) {
        float acc = xcnn_dw_b[o];
        #pragma unroll
        for (int k = 0; k < 9; ++k)
            acc = fmaf(buf[o][pn3[k]], xcnn_dw_w[o * 9 + k] * msk3[k], acc);
        xc2[o] = gelu_f(acc);
    }
    __syncthreads();
    #pragma unroll
    for (int o = 0; o < CH; ++o) buf[o][t] = xc2[o];
    __syncthreads();

    // ---- pooled[c] = mean over 64 pixels (thread t handles channel t)
    {
        float s = 0.f;
        for (int p = 0; p < PIX; ++p) s += buf[t][p];
        pooled_s[t] = s * (1.0f / PIX);
    }
    __syncthreads();

    // ---- channel-interaction SE gate (redundant per thread; uniform)
    {
        float t8[CI];
        #pragma unroll
        for (int m = 0; m < CI; ++m) t8[m] = ci_b1[m];
        for (int c = 0; c < CH; ++c) {
            float pv = pooled_s[c];
            #pragma unroll
            for (int m = 0; m < CI; ++m) t8[m] = fmaf(ci_w1[m * CH + c], pv, t8[m]);
        }
        float s = 0.f;
        #pragma unroll
        for (int m = 0; m < CI; ++m) s += t8[m];
        float mu = s * (1.0f / CI);
        float s2 = 0.f;
        #pragma unroll
        for (int m = 0; m < CI; ++m) { float d = t8[m] - mu; s2 = fmaf(d, d, s2); }
        float rstd = rsqrtf(s2 * (1.0f / CI) + EPSF);
        #pragma unroll
        for (int m = 0; m < CI; ++m)
            t8[m] = gelu_f((t8[m] - mu) * rstd * ci_ln_w[m] + ci_ln_b[m]);
        #pragma unroll
        for (int o = 0; o < HALF; ++o) {
            float a = ci_b2[o];
            #pragma unroll
            for (int m = 0; m < CI; ++m) a = fmaf(ci_w2[o * CI + m], t8[m], a);
            gate[o] *= sigmoid_f(a);
        }
    }

    // ---- SGU LayerNorm over half=32 (registers)
    {
        float s = 0.f;
        #pragma unroll
        for (int o = 0; o < HALF; ++o) s += gate[o];
        float mu = s * (1.0f / HALF);
        float s2 = 0.f;
        #pragma unroll
        for (int o = 0; o < HALF; ++o) { float d = gate[o] - mu; s2 = fmaf(d, d, s2); }
        float rstd = rsqrtf(s2 * (1.0f / HALF) + EPSF);
        #pragma unroll
        for (int o = 0; o < HALF; ++o)
            gate[o] = (gate[o] - mu) * rstd * sgu_ln_w[o] + sgu_ln_b[o];
    }
    __syncthreads();
    #pragma unroll
    for (int o = 0; o < HALF; ++o) buf[o][t] = gate[o];
    __syncthreads();

    // ---- g1 = dwb_w0 @ gate (no bias)
    float g1[HALF];
    #pragma unroll
    for (int o = 0; o < HALF; ++o) g1[o] = 0.f;
    for (int c = 0; c < HALF; ++c) {
        float gv = buf[c][t];
        #pragma unroll
        for (int o = 0; o < HALF; ++o) g1[o] = fmaf(dwb_w0[o * HALF + c], gv, g1[o]);
    }

    // ---- IDynamicDWConv kernel generation: 1x1 -> BN(eval) -> ReLU -> 1x1
    float t8b[CI];
    #pragma unroll
    for (int m = 0; m < CI; ++m) {
        float a = idw_b1[m];
        #pragma unroll
        for (int c = 0; c < HALF; ++c) a = fmaf(idw_w1[m * HALF + c], g1[c], a);
        a = a * (idw_bn_w[m] * 0.9999950000374997f) + idw_bn_b[m];  // 1/sqrt(1+1e-5)
        t8b[m] = fmaxf(a, 0.f);
    }
    __syncthreads();
    // stage g1 (rows 0..31) and wdyn (rows 32..80) -- wdyn via LDS avoids
    // runtime-indexed register array (rule: dyn-indexed arrays -> scratch)
    #pragma unroll
    for (int o = 0; o < HALF; ++o) buf[o][t] = g1[o];
    #pragma unroll
    for (int k = 0; k < KK; ++k) {
        float a = idw_b2[k];
        #pragma unroll
        for (int m = 0; m < CI; ++m) a = fmaf(idw_w2[k * CI + m], t8b[m], a);
        buf[HALF + k][t] = a;
    }
    __syncthreads();

    // ---- dynamic 7x7 depthwise (per-pixel kernels, shared across channels)
    float gd[HALF];
    #pragma unroll
    for (int o = 0; o < HALF; ++o) gd[o] = 0.f;
    for (int ki = 0; ki < 7; ++ki) {
        int r = py + ki - 3;
        for (int kj = 0; kj < 7; ++kj) {
            int cc = px + kj - 3;
            bool v = ((unsigned)r < 8u) && ((unsigned)cc < 8u);
            int pnn = v ? (r * 8 + cc) : 0;
            float wk = buf[HALF + ki * 7 + kj][t] * (v ? 1.0f : 0.0f);
            #pragma unroll
            for (int o = 0; o < HALF; ++o) gd[o] = fmaf(buf[o][pnn], wk, gd[o]);
        }
    }
    __syncthreads();
    #pragma unroll
    for (int o = 0; o < HALF; ++o) buf[o][t] = gd[o];
    __syncthreads();

    // ---- g2 = dwb_w2 @ gd ; x_sgu = g2 * res
    float sgu[HALF];
    #pragma unroll
    for (int o = 0; o < HALF; ++o) sgu[o] = 0.f;
    for (int c = 0; c < HALF; ++c) {
        float gv = buf[c][t];
        #pragma unroll
        for (int o = 0; o < HALF; ++o) sgu[o] = fmaf(dwb_w2[o * HALF + c], gv, sgu[o]);
    }
    #pragma unroll
    for (int o = 0; o < HALF; ++o) sgu[o] *= res[o];

    // ---- spatial interaction gate (per pixel)
    float siv;
    {
        float s1[SIM];
        #pragma unroll
        for (int m = 0; m < SIM; ++m) {
            float a = si_b1[m];
            #pragma unroll
            for (int c = 0; c < HALF; ++c) a = fmaf(si_w1[m * HALF + c], sgu[c], a);
            s1[m] = a;
        }
        float s = 0.f;
        #pragma unroll
        for (int m = 0; m < SIM; ++m) s += s1[m];
        float mu = s * (1.0f / SIM);
        float s2 = 0.f;
        #pragma unroll
        for (int m = 0; m < SIM; ++m) { float d = s1[m] - mu; s2 = fmaf(d, d, s2); }
        float rstd = rsqrtf(s2 * (1.0f / SIM) + EPSF);
        #pragma unroll
        for (int m = 0; m < SIM; ++m)
            s1[m] = gelu_f((s1[m] - mu) * rstd * si_ln_w[m] + si_ln_b[m]);
        float a = si_b2[0];
        #pragma unroll
        for (int m = 0; m < SIM; ++m) a = fmaf(si_w2[m], s1[m], a);
        siv = sigmoid_f(a);
    }

    // ---- xproj = (proj_w @ xc2 + proj_b) * siv   (stage xc2 for rolled matmul)
    __syncthreads();
    #pragma unroll
    for (int o = 0; o < CH; ++o) buf[o][t] = xc2[o];
    __syncthreads();
    float xp_[HALF];
    #pragma unroll
    for (int o = 0; o < HALF; ++o) xp_[o] = proj_b[o];
    for (int c = 0; c < CH; ++c) {
        float v = buf[c][t];
        #pragma unroll
        for (int o = 0; o < HALF; ++o) xp_[o] = fmaf(proj_w[o * CH + c], v, xp_[o]);
    }
    #pragma unroll
    for (int o = 0; o < HALF; ++o) xp_[o] *= siv;

    // ---- out = out_w @ concat(xproj, x_sgu) + out_b
    __syncthreads();
    #pragma unroll
    for (int o = 0; o < HALF; ++o) { buf[o][t] = xp_[o]; buf[o + HALF][t] = sgu[o]; }
    __syncthreads();
    float ov[CH];
    #pragma unroll
    for (int o = 0; o < CH; ++o) ov[o] = out_b[o];
    for (int c = 0; c < CH; ++c) {
        float v = buf[c][t];
        #pragma unroll
        for (int o = 0; o < CH; ++o) ov[o] = fmaf(out_w[o * CH + c], v, ov[o]);
    }
    float* op = out + bb * CH * HW + gy * 256 + gx;
    #pragma unroll
    for (int o = 0; o < CH; ++o) op[o * HW] = ov[o];
}

extern "C" void kernel_launch(void* const* d_in, const int* in_sizes, int n_in,
                              void* d_out, int out_size, void* d_ws, size_t ws_size,
                              hipStream_t stream) {
    const float* p[35];
    for (int i = 0; i < 35; ++i) p[i] = (const float*)d_in[i];
    const int B = in_sizes[0] / (64 * 256 * 256);   // = 4
    dim3 grid(B * 32 * 32), block(64);
    gmlp_fused<<<grid, block, 0, stream>>>(
        p[0],  p[1],  p[2],  p[3],  p[4],  p[5],  p[6],  p[7],  p[8],
        p[9],  p[10], p[11], p[12], p[13], p[14], p[15], p[16], p[17],
        p[18], p[19], p[20], p[21], p[22], p[23], p[24], p[25], p[26],
        p[27], p[28], p[29], p[30], p[31], p[32], p[33], p[34],
        (float*)d_out);
}

// Round 2
// 323.342 us; speedup vs baseline: 2.2702x; 2.2702x over previous
//
#include <hip/hip_runtime.h>
#include <math.h>

#define HWSZ 65536
#define EPSF 1e-5f

typedef __attribute__((ext_vector_type(8))) short bf8v;
typedef __attribute__((ext_vector_type(4))) float f4v;
typedef __attribute__((ext_vector_type(4))) unsigned int u4v;
typedef unsigned int uint32;

// ws offsets (bf16 elements)
#define W_HID_OFF   0
#define W_X1_OFF    4096
#define W_PROJ_OFF  8192
#define W_OUT_OFF   10240
#define W_DWB0_OFF  14336
#define W_DWB2_OFF  15360

__device__ __forceinline__ float gelu_f(float v){ return 0.5f*v*(1.0f+erff(v*0.7071067811865476f)); }
__device__ __forceinline__ float sigm(float v){ return 1.0f/(1.0f+expf(-v)); }
// bf16 pair unpack: lo = element 2q, hi = element 2q+1
__device__ __forceinline__ float bl(uint32 u){ return __uint_as_float(u<<16); }
__device__ __forceinline__ float bh(uint32 u){ return __uint_as_float(u & 0xffff0000u); }
// pack two f32 -> 2 bf16 (RNE) in one instruction
__device__ __forceinline__ uint32 pk2(float a, float b){
  uint32 r; asm("v_cvt_pk_bf16_f32 %0, %1, %2" : "=v"(r) : "v"(a), "v"(b)); return r;
}
// single f32 -> bf16 (RNE)
__device__ __forceinline__ unsigned short bfr(float x){
  uint32 u = __float_as_uint(x); u += 0x7fffu + ((u>>16)&1u); return (unsigned short)(u>>16);
}

__global__ void prep_w(const float* __restrict__ a0, const float* __restrict__ a1,
                       const float* __restrict__ a2, const float* __restrict__ a3,
                       const float* __restrict__ a4, const float* __restrict__ a5,
                       unsigned short* __restrict__ ws){
  int i = blockIdx.x*256 + threadIdx.x;
  if (i >= 16384) return;
  float v;
  if      (i < 4096)  v = a0[i];
  else if (i < 8192)  v = a1[i-4096];
  else if (i < 10240) v = a2[i-8192];
  else if (i < 14336) v = a3[i-10240];
  else if (i < 15360) v = a4[i-14336];
  else                v = a5[i-15360];
  ws[i] = bfr(v);
}

__global__ __launch_bounds__(64, 4)
void gmlp_fused(const float* __restrict__ x,
                const float* __restrict__ b_hid,
                const float* __restrict__ xcnn_b1,
                const float* __restrict__ xcnn_ln_w, const float* __restrict__ xcnn_ln_b,
                const float* __restrict__ xcnn_dw_w, const float* __restrict__ xcnn_dw_b,
                const float* __restrict__ ci_w1,   const float* __restrict__ ci_b1,
                const float* __restrict__ ci_ln_w, const float* __restrict__ ci_ln_b,
                const float* __restrict__ ci_w2,   const float* __restrict__ ci_b2,
                const float* __restrict__ si_w1,   const float* __restrict__ si_b1,
                const float* __restrict__ si_ln_w, const float* __restrict__ si_ln_b,
                const float* __restrict__ si_w2,   const float* __restrict__ si_b2,
                const float* __restrict__ proj_b,
                const float* __restrict__ out_b,
                const float* __restrict__ sgu_ln_w, const float* __restrict__ sgu_ln_b,
                const float* __restrict__ idw_w1,  const float* __restrict__ idw_b1,
                const float* __restrict__ idw_bn_w, const float* __restrict__ idw_bn_b,
                const float* __restrict__ idw_w2,  const float* __restrict__ idw_b2,
                const unsigned short* __restrict__ wsw,
                float* __restrict__ out)
{
    __shared__ unsigned short bufU[64][72];   // bf16, row = pixel, 144B stride
    __shared__ float pooled_s[64];

    const int t  = threadIdx.x;
    const int l4 = t & 15, g4 = t >> 4;
    const int py = t >> 3, px = t & 7;
    const int patch = blockIdx.x;
    const int pw = patch & 31, ph = (patch >> 5) & 31, bb = patch >> 10;
    const int gy = ph*8 + py, gx = pw*8 + px;
    const float* xin = x + bb*64*HWSZ + gy*256 + gx;

    // ---------------- P1: load x patch, stage bf16 ----------------
    #pragma unroll
    for (int c8 = 0; c8 < 8; ++c8) {
        u4v w;
        #pragma unroll
        for (int j = 0; j < 4; ++j) {
            int c = c8*8 + 2*j;
            w[j] = pk2(xin[c*HWSZ], xin[(c+1)*HWSZ]);
        }
        *(u4v*)&bufU[t][c8*8] = w;
    }
    __syncthreads();

    // ---------------- P2: hidden GEMM (64x64x64) + bias + gelu ----------------
    f4v acc[4][4];
    #pragma unroll
    for (int m = 0; m < 4; ++m)
        #pragma unroll
        for (int n = 0; n < 4; ++n)
            acc[m][n] = (f4v){0.f,0.f,0.f,0.f};
    #pragma unroll
    for (int s = 0; s < 2; ++s) {
        bf8v bf0 = *(const bf8v*)(wsw + W_HID_OFF + (0*16+l4)*64 + s*32 + g4*8);
        bf8v bf1 = *(const bf8v*)(wsw + W_HID_OFF + (1*16+l4)*64 + s*32 + g4*8);
        bf8v bf2 = *(const bf8v*)(wsw + W_HID_OFF + (2*16+l4)*64 + s*32 + g4*8);
        bf8v bf3 = *(const bf8v*)(wsw + W_HID_OFF + (3*16+l4)*64 + s*32 + g4*8);
        #pragma unroll
        for (int m = 0; m < 4; ++m) {
            bf8v a = *(const bf8v*)&bufU[m*16 + l4][s*32 + g4*8];
            acc[m][0] = __builtin_amdgcn_mfma_f32_16x16x32_bf16(a, bf0, acc[m][0], 0,0,0);
            acc[m][1] = __builtin_amdgcn_mfma_f32_16x16x32_bf16(a, bf1, acc[m][1], 0,0,0);
            acc[m][2] = __builtin_amdgcn_mfma_f32_16x16x32_bf16(a, bf2, acc[m][2], 0,0,0);
            acc[m][3] = __builtin_amdgcn_mfma_f32_16x16x32_bf16(a, bf3, acc[m][3], 0,0,0);
        }
    }
    {
        float bhid[4];
        #pragma unroll
        for (int n = 0; n < 4; ++n) bhid[n] = b_hid[n*16 + l4];
        #pragma unroll
        for (int m = 0; m < 4; ++m)
            #pragma unroll
            for (int n = 0; n < 4; ++n)
                #pragma unroll
                for (int r = 0; r < 4; ++r)
                    acc[m][n][r] = gelu_f(acc[m][n][r] + bhid[n]);
    }
    __syncthreads();
    #pragma unroll
    for (int m = 0; m < 4; ++m)
        #pragma unroll
        for (int n = 0; n < 4; ++n)
            #pragma unroll
            for (int r = 0; r < 4; ++r)
                bufU[m*16 + g4*4 + r][n*16 + l4] = bfr(acc[m][n][r]);
    __syncthreads();

    // readback own row packed: res = ch0..31 (hidpk[0..15]), gate = ch32..63 (hidpk[16..31])
    uint32 hidpk[32];
    #pragma unroll
    for (int q8 = 0; q8 < 8; ++q8) {
        u4v v = *(const u4v*)&bufU[t][q8*8];
        #pragma unroll
        for (int j = 0; j < 4; ++j) hidpk[q8*4 + j] = v[j];
    }

    // ---------------- P3: xcnn GEMM + bias, then per-pixel LN ----------------
    #pragma unroll
    for (int m = 0; m < 4; ++m)
        #pragma unroll
        for (int n = 0; n < 4; ++n)
            acc[m][n] = (f4v){0.f,0.f,0.f,0.f};
    #pragma unroll
    for (int s = 0; s < 2; ++s) {
        bf8v bf0 = *(const bf8v*)(wsw + W_X1_OFF + (0*16+l4)*64 + s*32 + g4*8);
        bf8v bf1 = *(const bf8v*)(wsw + W_X1_OFF + (1*16+l4)*64 + s*32 + g4*8);
        bf8v bf2 = *(const bf8v*)(wsw + W_X1_OFF + (2*16+l4)*64 + s*32 + g4*8);
        bf8v bf3 = *(const bf8v*)(wsw + W_X1_OFF + (3*16+l4)*64 + s*32 + g4*8);
        #pragma unroll
        for (int m = 0; m < 4; ++m) {
            bf8v a = *(const bf8v*)&bufU[m*16 + l4][s*32 + g4*8];
            acc[m][0] = __builtin_amdgcn_mfma_f32_16x16x32_bf16(a, bf0, acc[m][0], 0,0,0);
            acc[m][1] = __builtin_amdgcn_mfma_f32_16x16x32_bf16(a, bf1, acc[m][1], 0,0,0);
            acc[m][2] = __builtin_amdgcn_mfma_f32_16x16x32_bf16(a, bf2, acc[m][2], 0,0,0);
            acc[m][3] = __builtin_amdgcn_mfma_f32_16x16x32_bf16(a, bf3, acc[m][3], 0,0,0);
        }
    }
    {
        float bx[4];
        #pragma unroll
        for (int n = 0; n < 4; ++n) bx[n] = xcnn_b1[n*16 + l4];
        #pragma unroll
        for (int m = 0; m < 4; ++m)
            #pragma unroll
            for (int n = 0; n < 4; ++n)
                #pragma unroll
                for (int r = 0; r < 4; ++r)
                    acc[m][n][r] += bx[n];
    }
    __syncthreads();
    #pragma unroll
    for (int m = 0; m < 4; ++m)
        #pragma unroll
        for (int n = 0; n < 4; ++n)
            #pragma unroll
            for (int r = 0; r < 4; ++r)
                bufU[m*16 + g4*4 + r][n*16 + l4] = bfr(acc[m][n][r]);
    __syncthreads();
    {   // per-pixel channel LN from own row, restage post-LN
        uint32 xcpk[32];
        #pragma unroll
        for (int q8 = 0; q8 < 8; ++q8) {
            u4v v = *(const u4v*)&bufU[t][q8*8];
            #pragma unroll
            for (int j = 0; j < 4; ++j) xcpk[q8*4 + j] = v[j];
        }
        float s1 = 0.f;
        #pragma unroll
        for (int q = 0; q < 32; ++q) s1 += bl(xcpk[q]) + bh(xcpk[q]);
        float mu = s1 * (1.f/64.f);
        float q2 = 0.f;
        #pragma unroll
        for (int q = 0; q < 32; ++q) {
            float d0 = bl(xcpk[q]) - mu; q2 = fmaf(d0, d0, q2);
            float d1 = bh(xcpk[q]) - mu; q2 = fmaf(d1, d1, q2);
        }
        float rstd = rsqrtf(q2*(1.f/64.f) + EPSF);
        #pragma unroll
        for (int c8 = 0; c8 < 8; ++c8) {
            u4v w;
            #pragma unroll
            for (int j = 0; j < 4; ++j) {
                int q = c8*4 + j;
                float a = (bl(xcpk[q]) - mu)*rstd*xcnn_ln_w[2*q]   + xcnn_ln_b[2*q];
                float b = (bh(xcpk[q]) - mu)*rstd*xcnn_ln_w[2*q+1] + xcnn_ln_b[2*q+1];
                w[j] = pk2(a, b);
            }
            *(u4v*)&bufU[t][c8*8] = w;
        }
    }
    __syncthreads();

    // ---------------- P4: depthwise 3x3 + gelu (two 32-ch halves) ----------------
    int   pn3[9]; float msk3[9];
    #pragma unroll
    for (int ki = 0; ki < 3; ++ki)
        #pragma unroll
        for (int kj = 0; kj < 3; ++kj) {
            int r = py + ki - 1, cc = px + kj - 1;
            bool v = ((unsigned)r < 8u) && ((unsigned)cc < 8u);
            pn3[ki*3+kj] = v ? (r*8 + cc) : 0;
            msk3[ki*3+kj] = v ? 1.0f : 0.0f;
        }
    {
        float xh[32];
        // half A: channels 0..31
        #pragma unroll
        for (int o = 0; o < 32; ++o) xh[o] = xcnn_dw_b[o];
        #pragma unroll
        for (int k = 0; k < 9; ++k) {
            const unsigned short* rp = &bufU[pn3[k]][0];
            #pragma unroll
            for (int c8 = 0; c8 < 4; ++c8) {
                u4v v = *(const u4v*)(rp + c8*8);
                #pragma unroll
                for (int j = 0; j < 4; ++j) {
                    int c = c8*8 + 2*j;
                    xh[c]   = fmaf(bl(v[j]), xcnn_dw_w[c*9+k]*msk3[k],     xh[c]);
                    xh[c+1] = fmaf(bh(v[j]), xcnn_dw_w[(c+1)*9+k]*msk3[k], xh[c+1]);
                }
            }
        }
        #pragma unroll
        for (int o = 0; o < 32; ++o) xh[o] = gelu_f(xh[o]);
        __syncthreads();
        #pragma unroll
        for (int c8 = 0; c8 < 4; ++c8) {
            u4v w;
            #pragma unroll
            for (int j = 0; j < 4; ++j) w[j] = pk2(xh[c8*8+2*j], xh[c8*8+2*j+1]);
            *(u4v*)&bufU[t][c8*8] = w;
        }
        // half B: channels 32..63 (reads cols 32..63, untouched by half-A writes)
        #pragma unroll
        for (int o = 0; o < 32; ++o) xh[o] = xcnn_dw_b[32+o];
        #pragma unroll
        for (int k = 0; k < 9; ++k) {
            const unsigned short* rp = &bufU[pn3[k]][0];
            #pragma unroll
            for (int c8 = 0; c8 < 4; ++c8) {
                u4v v = *(const u4v*)(rp + 32 + c8*8);
                #pragma unroll
                for (int j = 0; j < 4; ++j) {
                    int c = c8*8 + 2*j;
                    xh[c]   = fmaf(bl(v[j]), xcnn_dw_w[(32+c)*9+k]*msk3[k],   xh[c]);
                    xh[c+1] = fmaf(bh(v[j]), xcnn_dw_w[(33+c)*9+k]*msk3[k],   xh[c+1]);
                }
            }
        }
        #pragma unroll
        for (int o = 0; o < 32; ++o) xh[o] = gelu_f(xh[o]);
        __syncthreads();
        #pragma unroll
        for (int c8 = 0; c8 < 4; ++c8) {
            u4v w;
            #pragma unroll
            for (int j = 0; j < 4; ++j) w[j] = pk2(xh[c8*8+2*j], xh[c8*8+2*j+1]);
            *(u4v*)&bufU[t][32 + c8*8] = w;
        }
    }
    __syncthreads();

    // ---------------- P4.5: pooled (col-sum) + proj GEMM ----------------
    {
        float ps = 0.f;
        for (int p = 0; p < 64; ++p) ps += bl((uint32)bufU[p][t]);
        pooled_s[t] = ps * (1.f/64.f);
    }
    f4v accp[4][2];
    #pragma unroll
    for (int m = 0; m < 4; ++m) { accp[m][0] = (f4v){0.f,0.f,0.f,0.f}; accp[m][1] = (f4v){0.f,0.f,0.f,0.f}; }
    #pragma unroll
    for (int s = 0; s < 2; ++s) {
        bf8v bf0 = *(const bf8v*)(wsw + W_PROJ_OFF + (0*16+l4)*64 + s*32 + g4*8);
        bf8v bf1 = *(const bf8v*)(wsw + W_PROJ_OFF + (1*16+l4)*64 + s*32 + g4*8);
        #pragma unroll
        for (int m = 0; m < 4; ++m) {
            bf8v a = *(const bf8v*)&bufU[m*16 + l4][s*32 + g4*8];
            accp[m][0] = __builtin_amdgcn_mfma_f32_16x16x32_bf16(a, bf0, accp[m][0], 0,0,0);
            accp[m][1] = __builtin_amdgcn_mfma_f32_16x16x32_bf16(a, bf1, accp[m][1], 0,0,0);
        }
    }
    {
        float bp0 = proj_b[l4], bp1 = proj_b[16 + l4];
        #pragma unroll
        for (int m = 0; m < 4; ++m)
            #pragma unroll
            for (int r = 0; r < 4; ++r) { accp[m][0][r] += bp0; accp[m][1][r] += bp1; }
    }
    __syncthreads();
    #pragma unroll
    for (int m = 0; m < 4; ++m)
        #pragma unroll
        for (int n = 0; n < 2; ++n)
            #pragma unroll
            for (int r = 0; r < 4; ++r)
                bufU[m*16 + g4*4 + r][n*16 + l4] = bfr(accp[m][n][r]);
    __syncthreads();
    uint32 xppk[16];
    #pragma unroll
    for (int q8 = 0; q8 < 4; ++q8) {
        u4v v = *(const u4v*)&bufU[t][q8*8];
        #pragma unroll
        for (int j = 0; j < 4; ++j) xppk[q8*4 + j] = v[j];
    }

    // ---------------- P5: SE channel gate + apply to gate ----------------
    float sg[32];
    {
        float t8[8];
        #pragma unroll
        for (int m = 0; m < 8; ++m) t8[m] = ci_b1[m];
        for (int c = 0; c < 64; ++c) {
            float pv = pooled_s[c];
            #pragma unroll
            for (int m = 0; m < 8; ++m) t8[m] = fmaf(ci_w1[m*64 + c], pv, t8[m]);
        }
        float s = 0.f;
        #pragma unroll
        for (int m = 0; m < 8; ++m) s += t8[m];
        float mu = s * 0.125f;
        float q2 = 0.f;
        #pragma unroll
        for (int m = 0; m < 8; ++m) { float d = t8[m]-mu; q2 = fmaf(d,d,q2); }
        float rstd = rsqrtf(q2*0.125f + EPSF);
        #pragma unroll
        for (int m = 0; m < 8; ++m) t8[m] = gelu_f((t8[m]-mu)*rstd*ci_ln_w[m] + ci_ln_b[m]);
        #pragma unroll
        for (int o = 0; o < 32; ++o) {
            float a = ci_b2[o];
            #pragma unroll
            for (int m = 0; m < 8; ++m) a = fmaf(ci_w2[o*8 + m], t8[m], a);
            float cg = sigm(a);
            uint32 pkv = hidpk[16 + o/2];
            float gv = (o & 1) ? bh(pkv) : bl(pkv);
            sg[o] = gv * cg;
        }
    }
    // SGU LayerNorm over 32
    {
        float s = 0.f;
        #pragma unroll
        for (int o = 0; o < 32; ++o) s += sg[o];
        float mu = s * (1.f/32.f);
        float q2 = 0.f;
        #pragma unroll
        for (int o = 0; o < 32; ++o) { float d = sg[o]-mu; q2 = fmaf(d,d,q2); }
        float rstd = rsqrtf(q2*(1.f/32.f) + EPSF);
        #pragma unroll
        for (int o = 0; o < 32; ++o) sg[o] = (sg[o]-mu)*rstd*sgu_ln_w[o] + sgu_ln_b[o];
    }
    __syncthreads();
    #pragma unroll
    for (int c8 = 0; c8 < 4; ++c8) {
        u4v w;
        #pragma unroll
        for (int j = 0; j < 4; ++j) w[j] = pk2(sg[c8*8+2*j], sg[c8*8+2*j+1]);
        *(u4v*)&bufU[t][c8*8] = w;
    }
    __syncthreads();

    // ---------------- P7: dwb_w0 GEMM (64x32x32, no bias) ----------------
    f4v accg[4][2];
    #pragma unroll
    for (int m = 0; m < 4; ++m) { accg[m][0] = (f4v){0.f,0.f,0.f,0.f}; accg[m][1] = (f4v){0.f,0.f,0.f,0.f}; }
    {
        bf8v bf0 = *(const bf8v*)(wsw + W_DWB0_OFF + (0*16+l4)*32 + g4*8);
        bf8v bf1 = *(const bf8v*)(wsw + W_DWB0_OFF + (1*16+l4)*32 + g4*8);
        #pragma unroll
        for (int m = 0; m < 4; ++m) {
            bf8v a = *(const bf8v*)&bufU[m*16 + l4][g4*8];
            accg[m][0] = __builtin_amdgcn_mfma_f32_16x16x32_bf16(a, bf0, accg[m][0], 0,0,0);
            accg[m][1] = __builtin_amdgcn_mfma_f32_16x16x32_bf16(a, bf1, accg[m][1], 0,0,0);
        }
    }
    __syncthreads();
    #pragma unroll
    for (int m = 0; m < 4; ++m)
        #pragma unroll
        for (int n = 0; n < 2; ++n)
            #pragma unroll
            for (int r = 0; r < 4; ++r)
                bufU[m*16 + g4*4 + r][n*16 + l4] = bfr(accg[m][n][r]);
    __syncthreads();
    uint32 g1pk[16];
    #pragma unroll
    for (int q8 = 0; q8 < 4; ++q8) {
        u4v v = *(const u4v*)&bufU[t][q8*8];
        #pragma unroll
        for (int j = 0; j < 4; ++j) g1pk[q8*4 + j] = v[j];
    }

    // ---------------- P8: idw kernel gen + dynamic 7x7 depthwise ----------------
    float t8b[8];
    #pragma unroll
    for (int m = 0; m < 8; ++m) t8b[m] = idw_b1[m];
    #pragma unroll
    for (int q = 0; q < 16; ++q) {
        float glo = bl(g1pk[q]), ghi = bh(g1pk[q]);
        #pragma unroll
        for (int m = 0; m < 8; ++m) {
            t8b[m] = fmaf(idw_w1[m*32 + 2*q],     glo, t8b[m]);
            t8b[m] = fmaf(idw_w1[m*32 + 2*q + 1], ghi, t8b[m]);
        }
    }
    #pragma unroll
    for (int m = 0; m < 8; ++m)
        t8b[m] = fmaxf(t8b[m]*(idw_bn_w[m]*0.9999950000374997f) + idw_bn_b[m], 0.f);

    float gd[32];
    #pragma unroll
    for (int o = 0; o < 32; ++o) gd[o] = 0.f;
    for (int ki = 0; ki < 7; ++ki) {
        int rr = py + ki - 3;
        for (int kj = 0; kj < 7; ++kj) {
            int cc = px + kj - 3;
            int k = ki*7 + kj;
            float wk = idw_b2[k];
            #pragma unroll
            for (int m = 0; m < 8; ++m) wk = fmaf(idw_w2[k*8 + m], t8b[m], wk);
            bool valid = ((unsigned)rr < 8u) && ((unsigned)cc < 8u);
            wk = valid ? wk : 0.f;
            int pnn = valid ? rr*8 + cc : 0;
            const unsigned short* rp = &bufU[pnn][0];
            #pragma unroll
            for (int c8 = 0; c8 < 4; ++c8) {
                u4v v = *(const u4v*)(rp + c8*8);
                #pragma unroll
                for (int j = 0; j < 4; ++j) {
                    gd[c8*8+2*j]   = fmaf(bl(v[j]), wk, gd[c8*8+2*j]);
                    gd[c8*8+2*j+1] = fmaf(bh(v[j]), wk, gd[c8*8+2*j+1]);
                }
            }
        }
    }
    __syncthreads();
    #pragma unroll
    for (int c8 = 0; c8 < 4; ++c8) {
        u4v w;
        #pragma unroll
        for (int j = 0; j < 4; ++j) w[j] = pk2(gd[c8*8+2*j], gd[c8*8+2*j+1]);
        *(u4v*)&bufU[t][c8*8] = w;
    }
    __syncthreads();

    // ---------------- P9: dwb_w2 GEMM (no bias) -> sgu = g2 * res ----------------
    #pragma unroll
    for (int m = 0; m < 4; ++m) { accg[m][0] = (f4v){0.f,0.f,0.f,0.f}; accg[m][1] = (f4v){0.f,0.f,0.f,0.f}; }
    {
        bf8v bf0 = *(const bf8v*)(wsw + W_DWB2_OFF + (0*16+l4)*32 + g4*8);
        bf8v bf1 = *(const bf8v*)(wsw + W_DWB2_OFF + (1*16+l4)*32 + g4*8);
        #pragma unroll
        for (int m = 0; m < 4; ++m) {
            bf8v a = *(const bf8v*)&bufU[m*16 + l4][g4*8];
            accg[m][0] = __builtin_amdgcn_mfma_f32_16x16x32_bf16(a, bf0, accg[m][0], 0,0,0);
            accg[m][1] = __builtin_amdgcn_mfma_f32_16x16x32_bf16(a, bf1, accg[m][1], 0,0,0);
        }
    }
    __syncthreads();
    #pragma unroll
    for (int m = 0; m < 4; ++m)
        #pragma unroll
        for (int n = 0; n < 2; ++n)
            #pragma unroll
            for (int r = 0; r < 4; ++r)
                bufU[m*16 + g4*4 + r][n*16 + l4] = bfr(accg[m][n][r]);
    __syncthreads();
    float sgu[32];
    #pragma unroll
    for (int q8 = 0; q8 < 4; ++q8) {
        u4v v = *(const u4v*)&bufU[t][q8*8];
        #pragma unroll
        for (int j = 0; j < 4; ++j) {
            int q = q8*4 + j;
            sgu[2*q]   = bl(v[j]) * bl(hidpk[q]);
            sgu[2*q+1] = bh(v[j]) * bh(hidpk[q]);
        }
    }

    // ---------------- P10: spatial-interaction gate ----------------
    float siv;
    {
        float s1[4];
        #pragma unroll
        for (int m = 0; m < 4; ++m) {
            float a = si_b1[m];
            #pragma unroll
            for (int c = 0; c < 32; ++c) a = fmaf(si_w1[m*32 + c], sgu[c], a);
            s1[m] = a;
        }
        float s = s1[0]+s1[1]+s1[2]+s1[3];
        float mu = s * 0.25f;
        float q2 = 0.f;
        #pragma unroll
        for (int m = 0; m < 4; ++m) { float d = s1[m]-mu; q2 = fmaf(d,d,q2); }
        float rstd = rsqrtf(q2*0.25f + EPSF);
        float a = si_b2[0];
        #pragma unroll
        for (int m = 0; m < 4; ++m)
            a = fmaf(si_w2[m], gelu_f((s1[m]-mu)*rstd*si_ln_w[m] + si_ln_b[m]), a);
        siv = sigm(a);
    }

    // ---------------- P11: stage concat(xp*siv, sgu), out GEMM, store ----------------
    __syncthreads();
    #pragma unroll
    for (int c8 = 0; c8 < 4; ++c8) {
        u4v w;
        #pragma unroll
        for (int j = 0; j < 4; ++j) {
            int q = c8*4 + j;
            w[j] = pk2(bl(xppk[q])*siv, bh(xppk[q])*siv);
        }
        *(u4v*)&bufU[t][c8*8] = w;
    }
    #pragma unroll
    for (int c8 = 0; c8 < 4; ++c8) {
        u4v w;
        #pragma unroll
        for (int j = 0; j < 4; ++j) w[j] = pk2(sgu[c8*8+2*j], sgu[c8*8+2*j+1]);
        *(u4v*)&bufU[t][32 + c8*8] = w;
    }
    __syncthreads();
    #pragma unroll
    for (int m = 0; m < 4; ++m)
        #pragma unroll
        for (int n = 0; n < 4; ++n)
            acc[m][n] = (f4v){0.f,0.f,0.f,0.f};
    #pragma unroll
    for (int s = 0; s < 2; ++s) {
        bf8v bf0 = *(const bf8v*)(wsw + W_OUT_OFF + (0*16+l4)*64 + s*32 + g4*8);
        bf8v bf1 = *(const bf8v*)(wsw + W_OUT_OFF + (1*16+l4)*64 + s*32 + g4*8);
        bf8v bf2 = *(const bf8v*)(wsw + W_OUT_OFF + (2*16+l4)*64 + s*32 + g4*8);
        bf8v bf3 = *(const bf8v*)(wsw + W_OUT_OFF + (3*16+l4)*64 + s*32 + g4*8);
        #pragma unroll
        for (int m = 0; m < 4; ++m) {
            bf8v a = *(const bf8v*)&bufU[m*16 + l4][s*32 + g4*8];
            acc[m][0] = __builtin_amdgcn_mfma_f32_16x16x32_bf16(a, bf0, acc[m][0], 0,0,0);
            acc[m][1] = __builtin_amdgcn_mfma_f32_16x16x32_bf16(a, bf1, acc[m][1], 0,0,0);
            acc[m][2] = __builtin_amdgcn_mfma_f32_16x16x32_bf16(a, bf2, acc[m][2], 0,0,0);
            acc[m][3] = __builtin_amdgcn_mfma_f32_16x16x32_bf16(a, bf3, acc[m][3], 0,0,0);
        }
    }
    {
        float bo[4];
        #pragma unroll
        for (int n = 0; n < 4; ++n) bo[n] = out_b[n*16 + l4];
        #pragma unroll
        for (int m = 0; m < 4; ++m)
            #pragma unroll
            for (int n = 0; n < 4; ++n)
                #pragma unroll
                for (int r = 0; r < 4; ++r)
                    acc[m][n][r] += bo[n];
    }
    __syncthreads();
    #pragma unroll
    for (int m = 0; m < 4; ++m)
        #pragma unroll
        for (int n = 0; n < 4; ++n)
            #pragma unroll
            for (int r = 0; r < 4; ++r)
                bufU[m*16 + g4*4 + r][n*16 + l4] = bfr(acc[m][n][r]);
    __syncthreads();
    {
        float* op = out + bb*64*HWSZ + gy*256 + gx;
        #pragma unroll
        for (int q8 = 0; q8 < 8; ++q8) {
            u4v v = *(const u4v*)&bufU[t][q8*8];
            #pragma unroll
            for (int j = 0; j < 4; ++j) {
                int c = q8*8 + 2*j;
                op[c*HWSZ]     = bl(v[j]);
                op[(c+1)*HWSZ] = bh(v[j]);
            }
        }
    }
}

extern "C" void kernel_launch(void* const* d_in, const int* in_sizes, int n_in,
                              void* d_out, int out_size, void* d_ws, size_t ws_size,
                              hipStream_t stream) {
    const float* p[35];
    for (int i = 0; i < 35; ++i) p[i] = (const float*)d_in[i];
    unsigned short* ws = (unsigned short*)d_ws;

    prep_w<<<64, 256, 0, stream>>>(p[1], p[3], p[21], p[23], p[27], p[34], ws);

    const int B = in_sizes[0] / (64 * 256 * 256);   // = 4
    dim3 grid(B * 32 * 32), block(64);
    gmlp_fused<<<grid, block, 0, stream>>>(
        p[0],  p[2],  p[4],  p[5],  p[6],  p[7],  p[8],
        p[9],  p[10], p[11], p[12], p[13], p[14],
        p[15], p[16], p[17], p[18], p[19], p[20],
        p[22], p[24], p[25], p[26],
        p[28], p[29], p[30], p[31], p[32], p[33],
        ws, (float*)d_out);
}

// Round 3
// 306.923 us; speedup vs baseline: 2.3917x; 1.0535x over previous
//
#include <hip/hip_runtime.h>
#include <math.h>

#define HWSZ 65536
#define EPSF 1e-5f
#define PSTR 4624   // shorts per patch LDS region: 64 rows * 72 + 16 pad (16B aligned)

typedef __attribute__((ext_vector_type(8))) short bf8v;
typedef __attribute__((ext_vector_type(4))) float f4v;
typedef __attribute__((ext_vector_type(4))) unsigned int u4v;
typedef unsigned int uint32;

// ws offsets (bf16 elements)
#define W_HID_OFF   0
#define W_X1_OFF    4096
#define W_PROJ_OFF  8192
#define W_OUT_OFF   10240
#define W_DWB0_OFF  14336
#define W_DWB2_OFF  15360

__device__ __forceinline__ float gelu_f(float v){ return 0.5f*v*(1.0f+erff(v*0.7071067811865476f)); }
__device__ __forceinline__ float sigm(float v){ return 1.0f/(1.0f+expf(-v)); }
__device__ __forceinline__ float bl(uint32 u){ return __uint_as_float(u<<16); }
__device__ __forceinline__ float bh(uint32 u){ return __uint_as_float(u & 0xffff0000u); }
__device__ __forceinline__ uint32 pk2(float a, float b){
  uint32 r; asm("v_cvt_pk_bf16_f32 %0, %1, %2" : "=v"(r) : "v"(a), "v"(b)); return r;
}
__device__ __forceinline__ unsigned short bfr(float x){
  uint32 u = __float_as_uint(x); u += 0x7fffu + ((u>>16)&1u); return (unsigned short)(u>>16);
}

// wave-local LDS fence: our patch region is touched only by this wave between
// real barriers; LDS ops of one wave execute in order, fence drains + blocks
// compiler motion (rule #18: sched_barrier after inline-asm lgkmcnt).
#define WSYNC() do { asm volatile("s_waitcnt lgkmcnt(0)" ::: "memory"); \
                     __builtin_amdgcn_sched_barrier(0); } while(0)

__global__ void prep_w(const float* __restrict__ a0, const float* __restrict__ a1,
                       const float* __restrict__ a2, const float* __restrict__ a3,
                       const float* __restrict__ a4, const float* __restrict__ a5,
                       unsigned short* __restrict__ ws){
  int i = blockIdx.x*256 + threadIdx.x;
  if (i >= 16384) return;
  float v;
  if      (i < 4096)  v = a0[i];
  else if (i < 8192)  v = a1[i-4096];
  else if (i < 10240) v = a2[i-8192];
  else if (i < 14336) v = a3[i-10240];
  else if (i < 15360) v = a4[i-14336];
  else                v = a5[i-15360];
  ws[i] = bfr(v);
}

__global__ __launch_bounds__(256, 4)
void gmlp_fused(const float* __restrict__ x,
                const float* __restrict__ b_hid,
                const float* __restrict__ xcnn_b1,
                const float* __restrict__ xcnn_ln_w, const float* __restrict__ xcnn_ln_b,
                const float* __restrict__ xcnn_dw_w, const float* __restrict__ xcnn_dw_b,
                const float* __restrict__ ci_w1,   const float* __restrict__ ci_b1,
                const float* __restrict__ ci_ln_w, const float* __restrict__ ci_ln_b,
                const float* __restrict__ ci_w2,   const float* __restrict__ ci_b2,
                const float* __restrict__ si_w1,   const float* __restrict__ si_b1,
                const float* __restrict__ si_ln_w, const float* __restrict__ si_ln_b,
                const float* __restrict__ si_w2,   const float* __restrict__ si_b2,
                const float* __restrict__ proj_b,
                const float* __restrict__ out_b,
                const float* __restrict__ sgu_ln_w, const float* __restrict__ sgu_ln_b,
                const float* __restrict__ idw_w1,  const float* __restrict__ idw_b1,
                const float* __restrict__ idw_bn_w, const float* __restrict__ idw_bn_b,
                const float* __restrict__ idw_w2,  const float* __restrict__ idw_b2,
                const unsigned short* __restrict__ wsw,
                float* __restrict__ out)
{
    __shared__ __align__(16) unsigned short bufS[4*PSTR];
    __shared__ float pooled_s[4][64];

    const int tx  = threadIdx.x;
    const int wid = tx >> 6;          // wave = patch within strip
    const int t   = tx & 63;          // lane = pixel
    const int l4  = t & 15, g4 = t >> 4;
    const int py  = t >> 3,  px = t & 7;

    const int bid   = blockIdx.x;     // grid = B * 32 * 8
    const int strip = bid & 7;
    const int ph    = (bid >> 3) & 31;
    const int bb    = bid >> 8;

    unsigned short* Wp = bufS + wid*PSTR;   // this wave's patch region

    // cooperative-I/O mapping (block covers strip 32 wide x 8 tall per channel)
    const int ty  = tx >> 5;          // row 0..7
    const int txx = tx & 31;          // col in strip
    const int lp  = txx >> 3;         // patch of this element
    const int lpx = txx & 7;
    const int yx  = ty*256 + txx;
    const float* xbase = x + (bb*64)*HWSZ + (ph*8)*256 + strip*32;
    unsigned short* ldst = bufS + lp*PSTR + (ty*8 + lpx)*72;

    // ---------------- P1: cooperative coalesced load (128B segments) ----------------
    #pragma unroll
    for (int c8 = 0; c8 < 8; ++c8) {
        u4v w;
        #pragma unroll
        for (int j = 0; j < 4; ++j) {
            int c = c8*8 + 2*j;
            w[j] = pk2(xbase[c*HWSZ + yx], xbase[(c+1)*HWSZ + yx]);
        }
        *(u4v*)(ldst + c8*8) = w;
    }
    __syncthreads();

    // ---------------- P2: hidden GEMM (64x64x64) + bias + gelu ----------------
    f4v acc[4][4];
    #pragma unroll
    for (int m = 0; m < 4; ++m)
        #pragma unroll
        for (int n = 0; n < 4; ++n)
            acc[m][n] = (f4v){0.f,0.f,0.f,0.f};
    #pragma unroll
    for (int s = 0; s < 2; ++s) {
        bf8v bf0 = *(const bf8v*)(wsw + W_HID_OFF + (0*16+l4)*64 + s*32 + g4*8);
        bf8v bf1 = *(const bf8v*)(wsw + W_HID_OFF + (1*16+l4)*64 + s*32 + g4*8);
        bf8v bf2 = *(const bf8v*)(wsw + W_HID_OFF + (2*16+l4)*64 + s*32 + g4*8);
        bf8v bf3 = *(const bf8v*)(wsw + W_HID_OFF + (3*16+l4)*64 + s*32 + g4*8);
        #pragma unroll
        for (int m = 0; m < 4; ++m) {
            bf8v a = *(const bf8v*)(Wp + (m*16 + l4)*72 + s*32 + g4*8);
            acc[m][0] = __builtin_amdgcn_mfma_f32_16x16x32_bf16(a, bf0, acc[m][0], 0,0,0);
            acc[m][1] = __builtin_amdgcn_mfma_f32_16x16x32_bf16(a, bf1, acc[m][1], 0,0,0);
            acc[m][2] = __builtin_amdgcn_mfma_f32_16x16x32_bf16(a, bf2, acc[m][2], 0,0,0);
            acc[m][3] = __builtin_amdgcn_mfma_f32_16x16x32_bf16(a, bf3, acc[m][3], 0,0,0);
        }
    }
    {
        float bhid[4];
        #pragma unroll
        for (int n = 0; n < 4; ++n) bhid[n] = b_hid[n*16 + l4];
        #pragma unroll
        for (int m = 0; m < 4; ++m)
            #pragma unroll
            for (int n = 0; n < 4; ++n)
                #pragma unroll
                for (int r = 0; r < 4; ++r)
                    acc[m][n][r] = gelu_f(acc[m][n][r] + bhid[n]);
    }
    WSYNC();
    #pragma unroll
    for (int m = 0; m < 4; ++m)
        #pragma unroll
        for (int n = 0; n < 4; ++n)
            #pragma unroll
            for (int r = 0; r < 4; ++r)
                Wp[(m*16 + g4*4 + r)*72 + n*16 + l4] = bfr(acc[m][n][r]);
    WSYNC();

    uint32 hidpk[32];   // res = [0..15], gate = [16..31]
    #pragma unroll
    for (int q8 = 0; q8 < 8; ++q8) {
        u4v v = *(const u4v*)(Wp + t*72 + q8*8);
        #pragma unroll
        for (int j = 0; j < 4; ++j) hidpk[q8*4 + j] = v[j];
    }

    // ---------------- P3: xcnn GEMM + bias, per-pixel LN ----------------
    #pragma unroll
    for (int m = 0; m < 4; ++m)
        #pragma unroll
        for (int n = 0; n < 4; ++n)
            acc[m][n] = (f4v){0.f,0.f,0.f,0.f};
    #pragma unroll
    for (int s = 0; s < 2; ++s) {
        bf8v bf0 = *(const bf8v*)(wsw + W_X1_OFF + (0*16+l4)*64 + s*32 + g4*8);
        bf8v bf1 = *(const bf8v*)(wsw + W_X1_OFF + (1*16+l4)*64 + s*32 + g4*8);
        bf8v bf2 = *(const bf8v*)(wsw + W_X1_OFF + (2*16+l4)*64 + s*32 + g4*8);
        bf8v bf3 = *(const bf8v*)(wsw + W_X1_OFF + (3*16+l4)*64 + s*32 + g4*8);
        #pragma unroll
        for (int m = 0; m < 4; ++m) {
            bf8v a = *(const bf8v*)(Wp + (m*16 + l4)*72 + s*32 + g4*8);
            acc[m][0] = __builtin_amdgcn_mfma_f32_16x16x32_bf16(a, bf0, acc[m][0], 0,0,0);
            acc[m][1] = __builtin_amdgcn_mfma_f32_16x16x32_bf16(a, bf1, acc[m][1], 0,0,0);
            acc[m][2] = __builtin_amdgcn_mfma_f32_16x16x32_bf16(a, bf2, acc[m][2], 0,0,0);
            acc[m][3] = __builtin_amdgcn_mfma_f32_16x16x32_bf16(a, bf3, acc[m][3], 0,0,0);
        }
    }
    {
        float bx[4];
        #pragma unroll
        for (int n = 0; n < 4; ++n) bx[n] = xcnn_b1[n*16 + l4];
        #pragma unroll
        for (int m = 0; m < 4; ++m)
            #pragma unroll
            for (int n = 0; n < 4; ++n)
                #pragma unroll
                for (int r = 0; r < 4; ++r)
                    acc[m][n][r] += bx[n];
    }
    WSYNC();
    #pragma unroll
    for (int m = 0; m < 4; ++m)
        #pragma unroll
        for (int n = 0; n < 4; ++n)
            #pragma unroll
            for (int r = 0; r < 4; ++r)
                Wp[(m*16 + g4*4 + r)*72 + n*16 + l4] = bfr(acc[m][n][r]);
    WSYNC();
    {   // per-pixel channel LN, restage
        uint32 xcpk[32];
        #pragma unroll
        for (int q8 = 0; q8 < 8; ++q8) {
            u4v v = *(const u4v*)(Wp + t*72 + q8*8);
            #pragma unroll
            for (int j = 0; j < 4; ++j) xcpk[q8*4 + j] = v[j];
        }
        float s1 = 0.f;
        #pragma unroll
        for (int q = 0; q < 32; ++q) s1 += bl(xcpk[q]) + bh(xcpk[q]);
        float mu = s1 * (1.f/64.f);
        float q2 = 0.f;
        #pragma unroll
        for (int q = 0; q < 32; ++q) {
            float d0 = bl(xcpk[q]) - mu; q2 = fmaf(d0, d0, q2);
            float d1 = bh(xcpk[q]) - mu; q2 = fmaf(d1, d1, q2);
        }
        float rstd = rsqrtf(q2*(1.f/64.f) + EPSF);
        #pragma unroll
        for (int c8 = 0; c8 < 8; ++c8) {
            u4v w;
            #pragma unroll
            for (int j = 0; j < 4; ++j) {
                int q = c8*4 + j;
                float a = (bl(xcpk[q]) - mu)*rstd*xcnn_ln_w[2*q]   + xcnn_ln_b[2*q];
                float b = (bh(xcpk[q]) - mu)*rstd*xcnn_ln_w[2*q+1] + xcnn_ln_b[2*q+1];
                w[j] = pk2(a, b);
            }
            *(u4v*)(Wp + t*72 + c8*8) = w;
        }
    }
    WSYNC();

    // ---------------- P4: depthwise 3x3 + gelu (two 32-ch halves) ----------------
    int   pn3[9]; float msk3[9];
    #pragma unroll
    for (int ki = 0; ki < 3; ++ki)
        #pragma unroll
        for (int kj = 0; kj < 3; ++kj) {
            int r = py + ki - 1, cc = px + kj - 1;
            bool v = ((unsigned)r < 8u) && ((unsigned)cc < 8u);
            pn3[ki*3+kj] = v ? (r*8 + cc) : 0;
            msk3[ki*3+kj] = v ? 1.0f : 0.0f;
        }
    {
        float xh[32];
        #pragma unroll
        for (int o = 0; o < 32; ++o) xh[o] = xcnn_dw_b[o];
        #pragma unroll
        for (int k = 0; k < 9; ++k) {
            const unsigned short* rp = Wp + pn3[k]*72;
            #pragma unroll
            for (int c8 = 0; c8 < 4; ++c8) {
                u4v v = *(const u4v*)(rp + c8*8);
                #pragma unroll
                for (int j = 0; j < 4; ++j) {
                    int c = c8*8 + 2*j;
                    xh[c]   = fmaf(bl(v[j]), xcnn_dw_w[c*9+k]*msk3[k],     xh[c]);
                    xh[c+1] = fmaf(bh(v[j]), xcnn_dw_w[(c+1)*9+k]*msk3[k], xh[c+1]);
                }
            }
        }
        #pragma unroll
        for (int o = 0; o < 32; ++o) xh[o] = gelu_f(xh[o]);
        WSYNC();
        #pragma unroll
        for (int c8 = 0; c8 < 4; ++c8) {
            u4v w;
            #pragma unroll
            for (int j = 0; j < 4; ++j) w[j] = pk2(xh[c8*8+2*j], xh[c8*8+2*j+1]);
            *(u4v*)(Wp + t*72 + c8*8) = w;
        }
        // half B: channels 32..63
        #pragma unroll
        for (int o = 0; o < 32; ++o) xh[o] = xcnn_dw_b[32+o];
        #pragma unroll
        for (int k = 0; k < 9; ++k) {
            const unsigned short* rp = Wp + pn3[k]*72;
            #pragma unroll
            for (int c8 = 0; c8 < 4; ++c8) {
                u4v v = *(const u4v*)(rp + 32 + c8*8);
                #pragma unroll
                for (int j = 0; j < 4; ++j) {
                    int c = c8*8 + 2*j;
                    xh[c]   = fmaf(bl(v[j]), xcnn_dw_w[(32+c)*9+k]*msk3[k], xh[c]);
                    xh[c+1] = fmaf(bh(v[j]), xcnn_dw_w[(33+c)*9+k]*msk3[k], xh[c+1]);
                }
            }
        }
        #pragma unroll
        for (int o = 0; o < 32; ++o) xh[o] = gelu_f(xh[o]);
        WSYNC();
        #pragma unroll
        for (int c8 = 0; c8 < 4; ++c8) {
            u4v w;
            #pragma unroll
            for (int j = 0; j < 4; ++j) w[j] = pk2(xh[c8*8+2*j], xh[c8*8+2*j+1]);
            *(u4v*)(Wp + t*72 + 32 + c8*8) = w;
        }
    }
    WSYNC();

    // ---------------- P4.5: pooled (channel mean) + proj GEMM ----------------
    {
        float ps = 0.f;
        for (int p = 0; p < 64; ++p) ps += bl((uint32)Wp[p*72 + t]);
        pooled_s[wid][t] = ps * (1.f/64.f);
    }
    f4v accp[4][2];
    #pragma unroll
    for (int m = 0; m < 4; ++m) { accp[m][0] = (f4v){0.f,0.f,0.f,0.f}; accp[m][1] = (f4v){0.f,0.f,0.f,0.f}; }
    #pragma unroll
    for (int s = 0; s < 2; ++s) {
        bf8v bf0 = *(const bf8v*)(wsw + W_PROJ_OFF + (0*16+l4)*64 + s*32 + g4*8);
        bf8v bf1 = *(const bf8v*)(wsw + W_PROJ_OFF + (1*16+l4)*64 + s*32 + g4*8);
        #pragma unroll
        for (int m = 0; m < 4; ++m) {
            bf8v a = *(const bf8v*)(Wp + (m*16 + l4)*72 + s*32 + g4*8);
            accp[m][0] = __builtin_amdgcn_mfma_f32_16x16x32_bf16(a, bf0, accp[m][0], 0,0,0);
            accp[m][1] = __builtin_amdgcn_mfma_f32_16x16x32_bf16(a, bf1, accp[m][1], 0,0,0);
        }
    }
    {
        float bp0 = proj_b[l4], bp1 = proj_b[16 + l4];
        #pragma unroll
        for (int m = 0; m < 4; ++m)
            #pragma unroll
            for (int r = 0; r < 4; ++r) { accp[m][0][r] += bp0; accp[m][1][r] += bp1; }
    }
    WSYNC();
    #pragma unroll
    for (int m = 0; m < 4; ++m)
        #pragma unroll
        for (int n = 0; n < 2; ++n)
            #pragma unroll
            for (int r = 0; r < 4; ++r)
                Wp[(m*16 + g4*4 + r)*72 + n*16 + l4] = bfr(accp[m][n][r]);
    WSYNC();
    uint32 xppk[16];
    #pragma unroll
    for (int q8 = 0; q8 < 4; ++q8) {
        u4v v = *(const u4v*)(Wp + t*72 + q8*8);
        #pragma unroll
        for (int j = 0; j < 4; ++j) xppk[q8*4 + j] = v[j];
    }

    // ---------------- P5: SE channel gate + SGU LN ----------------
    float sg[32];
    {
        float t8[8];
        #pragma unroll
        for (int m = 0; m < 8; ++m) t8[m] = ci_b1[m];
        for (int c = 0; c < 64; ++c) {
            float pv = pooled_s[wid][c];
            #pragma unroll
            for (int m = 0; m < 8; ++m) t8[m] = fmaf(ci_w1[m*64 + c], pv, t8[m]);
        }
        float s = 0.f;
        #pragma unroll
        for (int m = 0; m < 8; ++m) s += t8[m];
        float mu = s * 0.125f;
        float q2 = 0.f;
        #pragma unroll
        for (int m = 0; m < 8; ++m) { float d = t8[m]-mu; q2 = fmaf(d,d,q2); }
        float rstd = rsqrtf(q2*0.125f + EPSF);
        #pragma unroll
        for (int m = 0; m < 8; ++m) t8[m] = gelu_f((t8[m]-mu)*rstd*ci_ln_w[m] + ci_ln_b[m]);
        #pragma unroll
        for (int o = 0; o < 32; ++o) {
            float a = ci_b2[o];
            #pragma unroll
            for (int m = 0; m < 8; ++m) a = fmaf(ci_w2[o*8 + m], t8[m], a);
            float cg = sigm(a);
            uint32 pkv = hidpk[16 + o/2];
            float gv = (o & 1) ? bh(pkv) : bl(pkv);
            sg[o] = gv * cg;
        }
    }
    {
        float s = 0.f;
        #pragma unroll
        for (int o = 0; o < 32; ++o) s += sg[o];
        float mu = s * (1.f/32.f);
        float q2 = 0.f;
        #pragma unroll
        for (int o = 0; o < 32; ++o) { float d = sg[o]-mu; q2 = fmaf(d,d,q2); }
        float rstd = rsqrtf(q2*(1.f/32.f) + EPSF);
        #pragma unroll
        for (int o = 0; o < 32; ++o) sg[o] = (sg[o]-mu)*rstd*sgu_ln_w[o] + sgu_ln_b[o];
    }
    WSYNC();
    #pragma unroll
    for (int c8 = 0; c8 < 4; ++c8) {
        u4v w;
        #pragma unroll
        for (int j = 0; j < 4; ++j) w[j] = pk2(sg[c8*8+2*j], sg[c8*8+2*j+1]);
        *(u4v*)(Wp + t*72 + c8*8) = w;
    }
    WSYNC();

    // ---------------- P7: dwb_w0 GEMM (64x32x32) ----------------
    f4v accg[4][2];
    #pragma unroll
    for (int m = 0; m < 4; ++m) { accg[m][0] = (f4v){0.f,0.f,0.f,0.f}; accg[m][1] = (f4v){0.f,0.f,0.f,0.f}; }
    {
        bf8v bf0 = *(const bf8v*)(wsw + W_DWB0_OFF + (0*16+l4)*32 + g4*8);
        bf8v bf1 = *(const bf8v*)(wsw + W_DWB0_OFF + (1*16+l4)*32 + g4*8);
        #pragma unroll
        for (int m = 0; m < 4; ++m) {
            bf8v a = *(const bf8v*)(Wp + (m*16 + l4)*72 + g4*8);
            accg[m][0] = __builtin_amdgcn_mfma_f32_16x16x32_bf16(a, bf0, accg[m][0], 0,0,0);
            accg[m][1] = __builtin_amdgcn_mfma_f32_16x16x32_bf16(a, bf1, accg[m][1], 0,0,0);
        }
    }
    WSYNC();
    #pragma unroll
    for (int m = 0; m < 4; ++m)
        #pragma unroll
        for (int n = 0; n < 2; ++n)
            #pragma unroll
            for (int r = 0; r < 4; ++r)
                Wp[(m*16 + g4*4 + r)*72 + n*16 + l4] = bfr(accg[m][n][r]);
    WSYNC();
    uint32 g1pk[16];
    #pragma unroll
    for (int q8 = 0; q8 < 4; ++q8) {
        u4v v = *(const u4v*)(Wp + t*72 + q8*8);
        #pragma unroll
        for (int j = 0; j < 4; ++j) g1pk[q8*4 + j] = v[j];
    }

    // ---------------- P8: idw kernel gen + dynamic 7x7 depthwise ----------------
    float t8b[8];
    #pragma unroll
    for (int m = 0; m < 8; ++m) t8b[m] = idw_b1[m];
    #pragma unroll
    for (int q = 0; q < 16; ++q) {
        float glo = bl(g1pk[q]), ghi = bh(g1pk[q]);
        #pragma unroll
        for (int m = 0; m < 8; ++m) {
            t8b[m] = fmaf(idw_w1[m*32 + 2*q],     glo, t8b[m]);
            t8b[m] = fmaf(idw_w1[m*32 + 2*q + 1], ghi, t8b[m]);
        }
    }
    #pragma unroll
    for (int m = 0; m < 8; ++m)
        t8b[m] = fmaxf(t8b[m]*(idw_bn_w[m]*0.9999950000374997f) + idw_bn_b[m], 0.f);

    float gd[32];
    #pragma unroll
    for (int o = 0; o < 32; ++o) gd[o] = 0.f;
    for (int ki = 0; ki < 7; ++ki) {
        int rr = py + ki - 3;
        for (int kj = 0; kj < 7; ++kj) {
            int cc = px + kj - 3;
            int k = ki*7 + kj;
            float wk = idw_b2[k];
            #pragma unroll
            for (int m = 0; m < 8; ++m) wk = fmaf(idw_w2[k*8 + m], t8b[m], wk);
            bool valid = ((unsigned)rr < 8u) && ((unsigned)cc < 8u);
            wk = valid ? wk : 0.f;
            int pnn = valid ? rr*8 + cc : 0;
            const unsigned short* rp = Wp + pnn*72;
            #pragma unroll
            for (int c8 = 0; c8 < 4; ++c8) {
                u4v v = *(const u4v*)(rp + c8*8);
                #pragma unroll
                for (int j = 0; j < 4; ++j) {
                    gd[c8*8+2*j]   = fmaf(bl(v[j]), wk, gd[c8*8+2*j]);
                    gd[c8*8+2*j+1] = fmaf(bh(v[j]), wk, gd[c8*8+2*j+1]);
                }
            }
        }
    }
    WSYNC();
    #pragma unroll
    for (int c8 = 0; c8 < 4; ++c8) {
        u4v w;
        #pragma unroll
        for (int j = 0; j < 4; ++j) w[j] = pk2(gd[c8*8+2*j], gd[c8*8+2*j+1]);
        *(u4v*)(Wp + t*72 + c8*8) = w;
    }
    WSYNC();

    // ---------------- P9: dwb_w2 GEMM -> sgu = g2 * res ----------------
    #pragma unroll
    for (int m = 0; m < 4; ++m) { accg[m][0] = (f4v){0.f,0.f,0.f,0.f}; accg[m][1] = (f4v){0.f,0.f,0.f,0.f}; }
    {
        bf8v bf0 = *(const bf8v*)(wsw + W_DWB2_OFF + (0*16+l4)*32 + g4*8);
        bf8v bf1 = *(const bf8v*)(wsw + W_DWB2_OFF + (1*16+l4)*32 + g4*8);
        #pragma unroll
        for (int m = 0; m < 4; ++m) {
            bf8v a = *(const bf8v*)(Wp + (m*16 + l4)*72 + g4*8);
            accg[m][0] = __builtin_amdgcn_mfma_f32_16x16x32_bf16(a, bf0, accg[m][0], 0,0,0);
            accg[m][1] = __builtin_amdgcn_mfma_f32_16x16x32_bf16(a, bf1, accg[m][1], 0,0,0);
        }
    }
    WSYNC();
    #pragma unroll
    for (int m = 0; m < 4; ++m)
        #pragma unroll
        for (int n = 0; n < 2; ++n)
            #pragma unroll
            for (int r = 0; r < 4; ++r)
                Wp[(m*16 + g4*4 + r)*72 + n*16 + l4] = bfr(accg[m][n][r]);
    WSYNC();
    float sgu[32];
    #pragma unroll
    for (int q8 = 0; q8 < 4; ++q8) {
        u4v v = *(const u4v*)(Wp + t*72 + q8*8);
        #pragma unroll
        for (int j = 0; j < 4; ++j) {
            int q = q8*4 + j;
            sgu[2*q]   = bl(v[j]) * bl(hidpk[q]);
            sgu[2*q+1] = bh(v[j]) * bh(hidpk[q]);
        }
    }

    // ---------------- P10: spatial-interaction gate ----------------
    float siv;
    {
        float s1[4];
        #pragma unroll
        for (int m = 0; m < 4; ++m) {
            float a = si_b1[m];
            #pragma unroll
            for (int c = 0; c < 32; ++c) a = fmaf(si_w1[m*32 + c], sgu[c], a);
            s1[m] = a;
        }
        float s = s1[0]+s1[1]+s1[2]+s1[3];
        float mu = s * 0.25f;
        float q2 = 0.f;
        #pragma unroll
        for (int m = 0; m < 4; ++m) { float d = s1[m]-mu; q2 = fmaf(d,d,q2); }
        float rstd = rsqrtf(q2*0.25f + EPSF);
        float a = si_b2[0];
        #pragma unroll
        for (int m = 0; m < 4; ++m)
            a = fmaf(si_w2[m], gelu_f((s1[m]-mu)*rstd*si_ln_w[m] + si_ln_b[m]), a);
        siv = sigm(a);
    }

    // ---------------- P11: stage concat(xp*siv, sgu), out GEMM ----------------
    WSYNC();
    #pragma unroll
    for (int c8 = 0; c8 < 4; ++c8) {
        u4v w;
        #pragma unroll
        for (int j = 0; j < 4; ++j) {
            int q = c8*4 + j;
            w[j] = pk2(bl(xppk[q])*siv, bh(xppk[q])*siv);
        }
        *(u4v*)(Wp + t*72 + c8*8) = w;
    }
    #pragma unroll
    for (int c8 = 0; c8 < 4; ++c8) {
        u4v w;
        #pragma unroll
        for (int j = 0; j < 4; ++j) w[j] = pk2(sgu[c8*8+2*j], sgu[c8*8+2*j+1]);
        *(u4v*)(Wp + t*72 + 32 + c8*8) = w;
    }
    WSYNC();
    #pragma unroll
    for (int m = 0; m < 4; ++m)
        #pragma unroll
        for (int n = 0; n < 4; ++n)
            acc[m][n] = (f4v){0.f,0.f,0.f,0.f};
    #pragma unroll
    for (int s = 0; s < 2; ++s) {
        bf8v bf0 = *(const bf8v*)(wsw + W_OUT_OFF + (0*16+l4)*64 + s*32 + g4*8);
        bf8v bf1 = *(const bf8v*)(wsw + W_OUT_OFF + (1*16+l4)*64 + s*32 + g4*8);
        bf8v bf2 = *(const bf8v*)(wsw + W_OUT_OFF + (2*16+l4)*64 + s*32 + g4*8);
        bf8v bf3 = *(const bf8v*)(wsw + W_OUT_OFF + (3*16+l4)*64 + s*32 + g4*8);
        #pragma unroll
        for (int m = 0; m < 4; ++m) {
            bf8v a = *(const bf8v*)(Wp + (m*16 + l4)*72 + s*32 + g4*8);
            acc[m][0] = __builtin_amdgcn_mfma_f32_16x16x32_bf16(a, bf0, acc[m][0], 0,0,0);
            acc[m][1] = __builtin_amdgcn_mfma_f32_16x16x32_bf16(a, bf1, acc[m][1], 0,0,0);
            acc[m][2] = __builtin_amdgcn_mfma_f32_16x16x32_bf16(a, bf2, acc[m][2], 0,0,0);
            acc[m][3] = __builtin_amdgcn_mfma_f32_16x16x32_bf16(a, bf3, acc[m][3], 0,0,0);
        }
    }
    {
        float bo[4];
        #pragma unroll
        for (int n = 0; n < 4; ++n) bo[n] = out_b[n*16 + l4];
        #pragma unroll
        for (int m = 0; m < 4; ++m)
            #pragma unroll
            for (int n = 0; n < 4; ++n)
                #pragma unroll
                for (int r = 0; r < 4; ++r)
                    acc[m][n][r] += bo[n];
    }
    WSYNC();
    #pragma unroll
    for (int m = 0; m < 4; ++m)
        #pragma unroll
        for (int n = 0; n < 4; ++n)
            #pragma unroll
            for (int r = 0; r < 4; ++r)
                Wp[(m*16 + g4*4 + r)*72 + n*16 + l4] = bfr(acc[m][n][r]);
    __syncthreads();

    // ---------------- P12: cooperative coalesced store ----------------
    {
        float* obase = out + (bb*64)*HWSZ + (ph*8)*256 + strip*32;
        const unsigned short* lsrc = bufS + lp*PSTR + (ty*8 + lpx)*72;
        #pragma unroll
        for (int c8 = 0; c8 < 8; ++c8) {
            u4v v = *(const u4v*)(lsrc + c8*8);
            #pragma unroll
            for (int j = 0; j < 4; ++j) {
                int c = c8*8 + 2*j;
                obase[c*HWSZ + yx]     = bl(v[j]);
                obase[(c+1)*HWSZ + yx] = bh(v[j]);
            }
        }
    }
}

extern "C" void kernel_launch(void* const* d_in, const int* in_sizes, int n_in,
                              void* d_out, int out_size, void* d_ws, size_t ws_size,
                              hipStream_t stream) {
    const float* p[35];
    for (int i = 0; i < 35; ++i) p[i] = (const float*)d_in[i];
    unsigned short* ws = (unsigned short*)d_ws;

    prep_w<<<64, 256, 0, stream>>>(p[1], p[3], p[21], p[23], p[27], p[34], ws);

    const int B = in_sizes[0] / (64 * 256 * 256);   // = 4
    dim3 grid(B * 32 * 8), block(256);
    gmlp_fused<<<grid, block, 0, stream>>>(
        p[0],  p[2],  p[4],  p[5],  p[6],  p[7],  p[8],
        p[9],  p[10], p[11], p[12], p[13], p[14],
        p[15], p[16], p[17], p[18], p[19], p[20],
        p[22], p[24], p[25], p[26],
        p[28], p[29], p[30], p[31], p[32], p[33],
        ws, (float*)d_out);
}

// Round 4
// 113.278 us; speedup vs baseline: 6.4802x; 2.7095x over previous
//
#include <hip/hip_runtime.h>
#include <math.h>

#define HWSZ 65536
#define EPSF 1e-5f
#define PSTR 4624   // shorts per patch LDS region (64 rows * 72 + pad, 16B aligned)

typedef __attribute__((ext_vector_type(8))) short bf8v;
typedef __attribute__((ext_vector_type(4))) float f4v;
typedef __attribute__((ext_vector_type(4))) unsigned int u4v;
typedef unsigned int uint32;

// bf16 ws offsets (shorts)
#define W_HID_OFF   0
#define W_X1_OFF    4096
#define W_PROJ_OFF  8192
#define W_OUT_OFF   10240
#define W_DWB0_OFF  14336
#define W_DWB2_OFF  15360
// f32 ws region starts at float index 8192 (byte 32768); offsets below relative to wf
#define F_DWT   0      // dwT[k*64+c]     = xcnn_dw_w[c*9+k]      (576)
#define F_CI1T  576    // ci_w1T[c*8+m]   = ci_w1[m*64+c]         (512)
#define F_CI2T  1088   // ci_w2T[m*32+o]  = ci_w2[o*8+m]          (256)
#define F_IW1T  1344   // idw_w1T[c*8+m]  = idw_w1[m*32+c]        (256)
#define F_SI1T  1600   // si_w1T[c*4+m]   = si_w1[m*32+c]         (128)

__device__ __forceinline__ float sigm(float v){ return 1.0f/(1.0f+expf(-v)); }
__device__ __forceinline__ float bl(uint32 u){ return __uint_as_float(u<<16); }
__device__ __forceinline__ float bh(uint32 u){ return __uint_as_float(u & 0xffff0000u); }
__device__ __forceinline__ uint32 pk2(float a, float b){
  uint32 r; asm("v_cvt_pk_bf16_f32 %0, %1, %2" : "=v"(r) : "v"(a), "v"(b)); return r;
}
__device__ __forceinline__ unsigned short bfr(float x){
  uint32 u = __float_as_uint(x); u += 0x7fffu + ((u>>16)&1u); return (unsigned short)(u>>16);
}
// single shared gelu body (code-size: one erf expansion instead of ~35)
__device__ __attribute__((noinline)) f4v gelu4(f4v v){
  f4v r;
  #pragma unroll
  for (int i=0;i<4;++i) r[i] = 0.5f*v[i]*(1.0f+erff(v[i]*0.7071067811865476f));
  return r;
}

// wave-local LDS fence (our patch region is single-wave between real barriers)
#define WSYNC() asm volatile("s_waitcnt lgkmcnt(0)" ::: "memory")

__global__ void prep_w(const float* __restrict__ a0, const float* __restrict__ a1,
                       const float* __restrict__ a2, const float* __restrict__ a3,
                       const float* __restrict__ a4, const float* __restrict__ a5,
                       unsigned short* __restrict__ ws){
  int i = blockIdx.x*256 + threadIdx.x;
  if (i >= 16384) return;
  float v;
  if      (i < 4096)  v = a0[i];
  else if (i < 8192)  v = a1[i-4096];
  else if (i < 10240) v = a2[i-8192];
  else if (i < 14336) v = a3[i-10240];
  else if (i < 15360) v = a4[i-14336];
  else                v = a5[i-15360];
  ws[i] = bfr(v);
}

__global__ void prep_t(const float* __restrict__ dw, const float* __restrict__ ci1,
                       const float* __restrict__ ci2, const float* __restrict__ iw1,
                       const float* __restrict__ sw1, float* __restrict__ wf){
  int i = blockIdx.x*256 + threadIdx.x;
  if (i >= 1728) return;
  float v;
  if (i < 576)        { int k=i/64, c=i%64;            v = dw[c*9+k]; }
  else if (i < 1088)  { int j=i-576,  c=j/8, m=j%8;    v = ci1[m*64+c]; }
  else if (i < 1344)  { int j=i-1088, m=j/32, o=j%32;  v = ci2[o*8+m]; }
  else if (i < 1600)  { int j=i-1344, c=j/8, m=j%8;    v = iw1[m*32+c]; }
  else                { int j=i-1600, c=j/4, m=j%4;    v = sw1[m*32+c]; }
  wf[i] = v;
}

__global__ __launch_bounds__(256, 4)
void gmlp_fused(const float* __restrict__ x,
                const float* __restrict__ b_hid,
                const float* __restrict__ xcnn_b1,
                const float* __restrict__ xcnn_ln_w, const float* __restrict__ xcnn_ln_b,
                const float* __restrict__ xcnn_dw_b,
                const float* __restrict__ ci_b1,
                const float* __restrict__ ci_ln_w, const float* __restrict__ ci_ln_b,
                const float* __restrict__ ci_b2,
                const float* __restrict__ si_b1,
                const float* __restrict__ si_ln_w, const float* __restrict__ si_ln_b,
                const float* __restrict__ si_w2,   const float* __restrict__ si_b2,
                const float* __restrict__ proj_b,
                const float* __restrict__ out_b,
                const float* __restrict__ sgu_ln_w, const float* __restrict__ sgu_ln_b,
                const float* __restrict__ idw_b1,
                const float* __restrict__ idw_bn_w, const float* __restrict__ idw_bn_b,
                const float* __restrict__ idw_w2,  const float* __restrict__ idw_b2,
                const unsigned short* __restrict__ wsw,
                float* __restrict__ out)
{
    __shared__ __align__(16) unsigned short bufS[4*PSTR];
    __shared__ __align__(16) float pooled_s[4][64];
    __shared__ __align__(16) float segate_s[4][32];

    const float* wf = (const float*)wsw + 8192;

    const int tx  = threadIdx.x;
    const int wid = tx >> 6;
    const int t   = tx & 63;
    const int l4  = t & 15, g4 = t >> 4;
    const int py  = t >> 3,  px = t & 7;

    const int bid   = blockIdx.x;     // grid = B * 32 * 8
    const int strip = bid & 7;
    const int ph    = (bid >> 3) & 31;
    const int bb    = bid >> 8;

    unsigned short* Wp = bufS + wid*PSTR;

    const int ty  = tx >> 5;
    const int txx = tx & 31;
    const int lp  = txx >> 3;
    const int lpx = txx & 7;
    const int yx  = ty*256 + txx;
    const float* xbase = x + (bb*64)*HWSZ + (ph*8)*256 + strip*32;
    unsigned short* ldst = bufS + lp*PSTR + (ty*8 + lpx)*72;

    // ---------------- P1: cooperative coalesced load ----------------
    #pragma unroll 1
    for (int c8 = 0; c8 < 8; ++c8) {
        u4v w;
        #pragma unroll
        for (int j = 0; j < 4; ++j) {
            int c = c8*8 + 2*j;
            float a = __builtin_nontemporal_load(xbase + c*HWSZ + yx);
            float b = __builtin_nontemporal_load(xbase + (c+1)*HWSZ + yx);
            w[j] = pk2(a, b);
        }
        *(u4v*)(ldst + c8*8) = w;
    }
    __syncthreads();

    // ---------------- P2: hidden GEMM + bias + gelu ----------------
    f4v acc[4][4];
    #pragma unroll
    for (int m = 0; m < 4; ++m)
        #pragma unroll
        for (int n = 0; n < 4; ++n)
            acc[m][n] = (f4v){0.f,0.f,0.f,0.f};
    #pragma unroll 1
    for (int s = 0; s < 2; ++s) {
        bf8v bw[4]; bf8v av[4];
        #pragma unroll
        for (int n = 0; n < 4; ++n) bw[n] = *(const bf8v*)(wsw + W_HID_OFF + (n*16+l4)*64 + s*32 + g4*8);
        #pragma unroll
        for (int m = 0; m < 4; ++m) av[m] = *(const bf8v*)(Wp + (m*16 + l4)*72 + s*32 + g4*8);
        #pragma unroll
        for (int m = 0; m < 4; ++m)
            #pragma unroll
            for (int n = 0; n < 4; ++n)
                acc[m][n] = __builtin_amdgcn_mfma_f32_16x16x32_bf16(av[m], bw[n], acc[m][n], 0,0,0);
    }
    {
        float bhid[4];
        #pragma unroll
        for (int n = 0; n < 4; ++n) bhid[n] = b_hid[n*16 + l4];
        #pragma unroll
        for (int m = 0; m < 4; ++m)
            #pragma unroll
            for (int n = 0; n < 4; ++n) {
                f4v q;
                #pragma unroll
                for (int r = 0; r < 4; ++r) q[r] = acc[m][n][r] + bhid[n];
                acc[m][n] = gelu4(q);
            }
    }
    WSYNC();
    #pragma unroll
    for (int m = 0; m < 4; ++m)
        #pragma unroll
        for (int n = 0; n < 4; ++n)
            #pragma unroll
            for (int r = 0; r < 4; ++r)
                Wp[(m*16 + g4*4 + r)*72 + n*16 + l4] = bfr(acc[m][n][r]);
    WSYNC();

    uint32 hidpk[32];   // res = [0..15], gate = [16..31]
    #pragma unroll
    for (int q8 = 0; q8 < 8; ++q8) {
        u4v v = *(const u4v*)(Wp + t*72 + q8*8);
        #pragma unroll
        for (int j = 0; j < 4; ++j) hidpk[q8*4 + j] = v[j];
    }

    // ---------------- P3: xcnn GEMM + bias, per-pixel LN (LDS 3-pass) ----------------
    #pragma unroll
    for (int m = 0; m < 4; ++m)
        #pragma unroll
        for (int n = 0; n < 4; ++n)
            acc[m][n] = (f4v){0.f,0.f,0.f,0.f};
    #pragma unroll 1
    for (int s = 0; s < 2; ++s) {
        bf8v bw[4]; bf8v av[4];
        #pragma unroll
        for (int n = 0; n < 4; ++n) bw[n] = *(const bf8v*)(wsw + W_X1_OFF + (n*16+l4)*64 + s*32 + g4*8);
        #pragma unroll
        for (int m = 0; m < 4; ++m) av[m] = *(const bf8v*)(Wp + (m*16 + l4)*72 + s*32 + g4*8);
        #pragma unroll
        for (int m = 0; m < 4; ++m)
            #pragma unroll
            for (int n = 0; n < 4; ++n)
                acc[m][n] = __builtin_amdgcn_mfma_f32_16x16x32_bf16(av[m], bw[n], acc[m][n], 0,0,0);
    }
    {
        float bx[4];
        #pragma unroll
        for (int n = 0; n < 4; ++n) bx[n] = xcnn_b1[n*16 + l4];
        #pragma unroll
        for (int m = 0; m < 4; ++m)
            #pragma unroll
            for (int n = 0; n < 4; ++n)
                #pragma unroll
                for (int r = 0; r < 4; ++r)
                    acc[m][n][r] += bx[n];
    }
    WSYNC();
    #pragma unroll
    for (int m = 0; m < 4; ++m)
        #pragma unroll
        for (int n = 0; n < 4; ++n)
            #pragma unroll
            for (int r = 0; r < 4; ++r)
                Wp[(m*16 + g4*4 + r)*72 + n*16 + l4] = bfr(acc[m][n][r]);
    WSYNC();
    {   // LN over 64 channels, 3 rolled passes over own row
        float s = 0.f;
        #pragma unroll 1
        for (int q8 = 0; q8 < 8; ++q8) {
            u4v v = *(const u4v*)(Wp + t*72 + q8*8);
            #pragma unroll
            for (int j = 0; j < 4; ++j) s += bl(v[j]) + bh(v[j]);
        }
        float mu = s * (1.f/64.f);
        float s2 = 0.f;
        #pragma unroll 1
        for (int q8 = 0; q8 < 8; ++q8) {
            u4v v = *(const u4v*)(Wp + t*72 + q8*8);
            #pragma unroll
            for (int j = 0; j < 4; ++j) {
                float d0 = bl(v[j]) - mu, d1 = bh(v[j]) - mu;
                s2 = fmaf(d0, d0, fmaf(d1, d1, s2));
            }
        }
        float rstd = rsqrtf(s2*(1.f/64.f) + EPSF);
        #pragma unroll 1
        for (int q8 = 0; q8 < 8; ++q8) {
            u4v v = *(const u4v*)(Wp + t*72 + q8*8);
            u4v w;
            #pragma unroll
            for (int j = 0; j < 4; ++j) {
                int c = q8*8 + 2*j;
                float a = (bl(v[j]) - mu)*rstd*xcnn_ln_w[c]   + xcnn_ln_b[c];
                float b = (bh(v[j]) - mu)*rstd*xcnn_ln_w[c+1] + xcnn_ln_b[c+1];
                w[j] = pk2(a, b);
            }
            *(u4v*)(Wp + t*72 + q8*8) = w;   // in-place, own row
        }
    }
    WSYNC();

    // ---------------- P4: depthwise 3x3 + gelu (two 32-ch halves) ----------------
    #pragma unroll 1
    for (int h = 0; h < 2; ++h) {
        float xh[32];
        #pragma unroll
        for (int o = 0; o < 32; ++o) xh[o] = xcnn_dw_b[h*32 + o];
        #pragma unroll 1
        for (int ki = 0; ki < 3; ++ki) {
            #pragma unroll 1
            for (int kj = 0; kj < 3; ++kj) {
                int rr = py + ki - 1, cc = px + kj - 1;
                bool val = ((unsigned)rr < 8u) && ((unsigned)cc < 8u);
                float mk = val ? 1.0f : 0.0f;
                int pnn = val ? rr*8 + cc : 0;
                const unsigned short* rp = Wp + pnn*72 + h*32;
                const float* wp = wf + F_DWT + (ki*3+kj)*64 + h*32;
                #pragma unroll
                for (int c8 = 0; c8 < 4; ++c8) {
                    u4v v = *(const u4v*)(rp + c8*8);
                    #pragma unroll
                    for (int j = 0; j < 4; ++j) {
                        int c = c8*8 + 2*j;
                        xh[c]   = fmaf(bl(v[j]), wp[c]*mk,   xh[c]);
                        xh[c+1] = fmaf(bh(v[j]), wp[c+1]*mk, xh[c+1]);
                    }
                }
            }
        }
        #pragma unroll
        for (int g = 0; g < 8; ++g) {
            f4v q = (f4v){xh[4*g], xh[4*g+1], xh[4*g+2], xh[4*g+3]};
            q = gelu4(q);
            xh[4*g]=q[0]; xh[4*g+1]=q[1]; xh[4*g+2]=q[2]; xh[4*g+3]=q[3];
        }
        WSYNC();   // all taps of this half read before overwriting cols h*32..
        #pragma unroll
        for (int c8 = 0; c8 < 4; ++c8) {
            u4v w;
            #pragma unroll
            for (int j = 0; j < 4; ++j) w[j] = pk2(xh[c8*8+2*j], xh[c8*8+2*j+1]);
            *(u4v*)(Wp + t*72 + h*32 + c8*8) = w;
        }
    }
    WSYNC();

    // ---------------- P4.5: pooled (channel mean) + proj GEMM ----------------
    {
        float ps = 0.f;
        #pragma unroll 1
        for (int p8 = 0; p8 < 8; ++p8) {
            #pragma unroll
            for (int q = 0; q < 8; ++q) ps += bl((uint32)Wp[(p8*8+q)*72 + t]);
        }
        pooled_s[wid][t] = ps * (1.f/64.f);
    }
    f4v accp[4][2];
    #pragma unroll
    for (int m = 0; m < 4; ++m) { accp[m][0] = (f4v){0.f,0.f,0.f,0.f}; accp[m][1] = (f4v){0.f,0.f,0.f,0.f}; }
    #pragma unroll 1
    for (int s = 0; s < 2; ++s) {
        bf8v bw[2]; bf8v av[4];
        #pragma unroll
        for (int n = 0; n < 2; ++n) bw[n] = *(const bf8v*)(wsw + W_PROJ_OFF + (n*16+l4)*64 + s*32 + g4*8);
        #pragma unroll
        for (int m = 0; m < 4; ++m) av[m] = *(const bf8v*)(Wp + (m*16 + l4)*72 + s*32 + g4*8);
        #pragma unroll
        for (int m = 0; m < 4; ++m)
            #pragma unroll
            for (int n = 0; n < 2; ++n)
                accp[m][n] = __builtin_amdgcn_mfma_f32_16x16x32_bf16(av[m], bw[n], accp[m][n], 0,0,0);
    }
    {
        float bp0 = proj_b[l4], bp1 = proj_b[16 + l4];
        #pragma unroll
        for (int m = 0; m < 4; ++m)
            #pragma unroll
            for (int r = 0; r < 4; ++r) { accp[m][0][r] += bp0; accp[m][1][r] += bp1; }
    }
    WSYNC();
    #pragma unroll
    for (int m = 0; m < 4; ++m)
        #pragma unroll
        for (int n = 0; n < 2; ++n)
            #pragma unroll
            for (int r = 0; r < 4; ++r)
                Wp[(m*16 + g4*4 + r)*72 + n*16 + l4] = bfr(accp[m][n][r]);
    WSYNC();
    uint32 xppk[16];
    #pragma unroll
    for (int q8 = 0; q8 < 4; ++q8) {
        u4v v = *(const u4v*)(Wp + t*72 + q8*8);
        #pragma unroll
        for (int j = 0; j < 4; ++j) xppk[q8*4 + j] = v[j];
    }

    // ---------------- P5: SE gate (rolled matvec + distributed sigmoid) ----------------
    {
        float t8[8];
        #pragma unroll
        for (int m = 0; m < 8; ++m) t8[m] = ci_b1[m];
        #pragma unroll 1
        for (int c4 = 0; c4 < 16; ++c4) {
            f4v pv = *(const f4v*)&pooled_s[wid][c4*4];
            #pragma unroll
            for (int j = 0; j < 4; ++j)
                #pragma unroll
                for (int m = 0; m < 8; ++m)
                    t8[m] = fmaf(wf[F_CI1T + (c4*4+j)*8 + m], pv[j], t8[m]);
        }
        float s = 0.f;
        #pragma unroll
        for (int m = 0; m < 8; ++m) s += t8[m];
        float mu = s * 0.125f;
        float q2 = 0.f;
        #pragma unroll
        for (int m = 0; m < 8; ++m) { float d = t8[m]-mu; q2 = fmaf(d,d,q2); }
        float rstd = rsqrtf(q2*0.125f + EPSF);
        #pragma unroll
        for (int m = 0; m < 8; ++m) t8[m] = (t8[m]-mu)*rstd*ci_ln_w[m] + ci_ln_b[m];
        f4v qa = gelu4((f4v){t8[0],t8[1],t8[2],t8[3]});
        f4v qb = gelu4((f4v){t8[4],t8[5],t8[6],t8[7]});
        t8[0]=qa[0]; t8[1]=qa[1]; t8[2]=qa[2]; t8[3]=qa[3];
        t8[4]=qb[0]; t8[5]=qb[1]; t8[6]=qb[2]; t8[7]=qb[3];
        if (t < 32) {
            float a = ci_b2[t];
            #pragma unroll
            for (int m = 0; m < 8; ++m) a = fmaf(wf[F_CI2T + m*32 + t], t8[m], a);
            segate_s[wid][t] = sigm(a);
        }
    }
    WSYNC();
    float sg[32];
    #pragma unroll
    for (int g = 0; g < 8; ++g) {
        f4v e = *(const f4v*)&segate_s[wid][g*4];
        #pragma unroll
        for (int r = 0; r < 4; ++r) {
            int o = g*4 + r;
            uint32 pkv = hidpk[16 + o/2];
            float gv = (o & 1) ? bh(pkv) : bl(pkv);
            sg[o] = gv * e[r];
        }
    }
    {   // SGU LayerNorm over 32
        float s = 0.f;
        #pragma unroll
        for (int o = 0; o < 32; ++o) s += sg[o];
        float mu = s * (1.f/32.f);
        float q2 = 0.f;
        #pragma unroll
        for (int o = 0; o < 32; ++o) { float d = sg[o]-mu; q2 = fmaf(d,d,q2); }
        float rstd = rsqrtf(q2*(1.f/32.f) + EPSF);
        #pragma unroll
        for (int o = 0; o < 32; ++o) sg[o] = (sg[o]-mu)*rstd*sgu_ln_w[o] + sgu_ln_b[o];
    }
    WSYNC();
    #pragma unroll
    for (int c8 = 0; c8 < 4; ++c8) {
        u4v w;
        #pragma unroll
        for (int j = 0; j < 4; ++j) w[j] = pk2(sg[c8*8+2*j], sg[c8*8+2*j+1]);
        *(u4v*)(Wp + t*72 + c8*8) = w;
    }
    WSYNC();

    // ---------------- P7: dwb_w0 GEMM (64x32x32) ----------------
    f4v accg[4][2];
    #pragma unroll
    for (int m = 0; m < 4; ++m) { accg[m][0] = (f4v){0.f,0.f,0.f,0.f}; accg[m][1] = (f4v){0.f,0.f,0.f,0.f}; }
    {
        bf8v bw[2]; bf8v av[4];
        #pragma unroll
        for (int n = 0; n < 2; ++n) bw[n] = *(const bf8v*)(wsw + W_DWB0_OFF + (n*16+l4)*32 + g4*8);
        #pragma unroll
        for (int m = 0; m < 4; ++m) av[m] = *(const bf8v*)(Wp + (m*16 + l4)*72 + g4*8);
        #pragma unroll
        for (int m = 0; m < 4; ++m)
            #pragma unroll
            for (int n = 0; n < 2; ++n)
                accg[m][n] = __builtin_amdgcn_mfma_f32_16x16x32_bf16(av[m], bw[n], accg[m][n], 0,0,0);
    }
    WSYNC();
    #pragma unroll
    for (int m = 0; m < 4; ++m)
        #pragma unroll
        for (int n = 0; n < 2; ++n)
            #pragma unroll
            for (int r = 0; r < 4; ++r)
                Wp[(m*16 + g4*4 + r)*72 + n*16 + l4] = bfr(accg[m][n][r]);
    WSYNC();

    // ---------------- P8: idw kernel gen (rolled) + dynamic 7x7 (rolled) ----------------
    float t8b[8];
    #pragma unroll
    for (int m = 0; m < 8; ++m) t8b[m] = idw_b1[m];
    #pragma unroll 1
    for (int c8 = 0; c8 < 4; ++c8) {
        u4v v = *(const u4v*)(Wp + t*72 + c8*8);
        #pragma unroll
        for (int j = 0; j < 4; ++j) {
            int c = c8*8 + 2*j;
            float glo = bl(v[j]), ghi = bh(v[j]);
            #pragma unroll
            for (int m = 0; m < 8; ++m) {
                t8b[m] = fmaf(wf[F_IW1T + c*8 + m],     glo, t8b[m]);
                t8b[m] = fmaf(wf[F_IW1T + (c+1)*8 + m], ghi, t8b[m]);
            }
        }
    }
    #pragma unroll
    for (int m = 0; m < 8; ++m)
        t8b[m] = fmaxf(t8b[m]*(idw_bn_w[m]*0.9999950000374997f) + idw_bn_b[m], 0.f);

    float gd[32];
    #pragma unroll
    for (int o = 0; o < 32; ++o) gd[o] = 0.f;
    #pragma unroll 1
    for (int ki = 0; ki < 7; ++ki) {
        #pragma unroll 1
        for (int kj = 0; kj < 7; ++kj) {
            int rr = py + ki - 3, cc = px + kj - 3;
            int k = ki*7 + kj;
            float wk = idw_b2[k];
            #pragma unroll
            for (int m = 0; m < 8; ++m) wk = fmaf(idw_w2[k*8 + m], t8b[m], wk);
            bool valid = ((unsigned)rr < 8u) && ((unsigned)cc < 8u);
            wk = valid ? wk : 0.f;
            int pnn = valid ? rr*8 + cc : 0;
            const unsigned short* rp = Wp + pnn*72;
            #pragma unroll
            for (int c8 = 0; c8 < 4; ++c8) {
                u4v v = *(const u4v*)(rp + c8*8);
                #pragma unroll
                for (int j = 0; j < 4; ++j) {
                    gd[c8*8+2*j]   = fmaf(bl(v[j]), wk, gd[c8*8+2*j]);
                    gd[c8*8+2*j+1] = fmaf(bh(v[j]), wk, gd[c8*8+2*j+1]);
                }
            }
        }
    }
    WSYNC();
    #pragma unroll
    for (int c8 = 0; c8 < 4; ++c8) {
        u4v w;
        #pragma unroll
        for (int j = 0; j < 4; ++j) w[j] = pk2(gd[c8*8+2*j], gd[c8*8+2*j+1]);
        *(u4v*)(Wp + t*72 + c8*8) = w;
    }
    WSYNC();

    // ---------------- P9: dwb_w2 GEMM -> sgu = g2 * res ----------------
    #pragma unroll
    for (int m = 0; m < 4; ++m) { accg[m][0] = (f4v){0.f,0.f,0.f,0.f}; accg[m][1] = (f4v){0.f,0.f,0.f,0.f}; }
    {
        bf8v bw[2]; bf8v av[4];
        #pragma unroll
        for (int n = 0; n < 2; ++n) bw[n] = *(const bf8v*)(wsw + W_DWB2_OFF + (n*16+l4)*32 + g4*8);
        #pragma unroll
        for (int m = 0; m < 4; ++m) av[m] = *(const bf8v*)(Wp + (m*16 + l4)*72 + g4*8);
        #pragma unroll
        for (int m = 0; m < 4; ++m)
            #pragma unroll
            for (int n = 0; n < 2; ++n)
                accg[m][n] = __builtin_amdgcn_mfma_f32_16x16x32_bf16(av[m], bw[n], accg[m][n], 0,0,0);
    }
    WSYNC();
    #pragma unroll
    for (int m = 0; m < 4; ++m)
        #pragma unroll
        for (int n = 0; n < 2; ++n)
            #pragma unroll
            for (int r = 0; r < 4; ++r)
                Wp[(m*16 + g4*4 + r)*72 + n*16 + l4] = bfr(accg[m][n][r]);
    WSYNC();
    float sgu[32];
    #pragma unroll
    for (int q8 = 0; q8 < 4; ++q8) {
        u4v v = *(const u4v*)(Wp + t*72 + q8*8);
        #pragma unroll
        for (int j = 0; j < 4; ++j) {
            int q = q8*4 + j;
            sgu[2*q]   = bl(v[j]) * bl(hidpk[q]);
            sgu[2*q+1] = bh(v[j]) * bh(hidpk[q]);
        }
    }
    WSYNC();

    // ---------------- P10: stage sgu (cols 32..63), si gate, stage xp*siv ----------------
    #pragma unroll
    for (int c8 = 0; c8 < 4; ++c8) {
        u4v w;
        #pragma unroll
        for (int j = 0; j < 4; ++j) w[j] = pk2(sgu[c8*8+2*j], sgu[c8*8+2*j+1]);
        *(u4v*)(Wp + t*72 + 32 + c8*8) = w;
    }
    WSYNC();
    float siv;
    {
        float s1[4];
        #pragma unroll
        for (int m = 0; m < 4; ++m) s1[m] = si_b1[m];
        #pragma unroll 1
        for (int c8 = 0; c8 < 4; ++c8) {
            u4v v = *(const u4v*)(Wp + t*72 + 32 + c8*8);
            #pragma unroll
            for (int j = 0; j < 4; ++j) {
                int c = c8*8 + 2*j;
                float a0 = bl(v[j]), a1 = bh(v[j]);
                #pragma unroll
                for (int m = 0; m < 4; ++m) {
                    s1[m] = fmaf(wf[F_SI1T + c*4 + m],     a0, s1[m]);
                    s1[m] = fmaf(wf[F_SI1T + (c+1)*4 + m], a1, s1[m]);
                }
            }
        }
        float s = s1[0]+s1[1]+s1[2]+s1[3];
        float mu = s * 0.25f;
        float q2 = 0.f;
        #pragma unroll
        for (int m = 0; m < 4; ++m) { float d = s1[m]-mu; q2 = fmaf(d,d,q2); }
        float rstd = rsqrtf(q2*0.25f + EPSF);
        f4v q;
        #pragma unroll
        for (int m = 0; m < 4; ++m) q[m] = (s1[m]-mu)*rstd*si_ln_w[m] + si_ln_b[m];
        q = gelu4(q);
        float a = si_b2[0];
        #pragma unroll
        for (int m = 0; m < 4; ++m) a = fmaf(si_w2[m], q[m], a);
        siv = sigm(a);
    }
    #pragma unroll
    for (int c8 = 0; c8 < 4; ++c8) {
        u4v w;
        #pragma unroll
        for (int j = 0; j < 4; ++j) {
            int q = c8*4 + j;
            w[j] = pk2(bl(xppk[q])*siv, bh(xppk[q])*siv);
        }
        *(u4v*)(Wp + t*72 + c8*8) = w;
    }
    WSYNC();

    // ---------------- P11: out GEMM + bias ----------------
    #pragma unroll
    for (int m = 0; m < 4; ++m)
        #pragma unroll
        for (int n = 0; n < 4; ++n)
            acc[m][n] = (f4v){0.f,0.f,0.f,0.f};
    #pragma unroll 1
    for (int s = 0; s < 2; ++s) {
        bf8v bw[4]; bf8v av[4];
        #pragma unroll
        for (int n = 0; n < 4; ++n) bw[n] = *(const bf8v*)(wsw + W_OUT_OFF + (n*16+l4)*64 + s*32 + g4*8);
        #pragma unroll
        for (int m = 0; m < 4; ++m) av[m] = *(const bf8v*)(Wp + (m*16 + l4)*72 + s*32 + g4*8);
        #pragma unroll
        for (int m = 0; m < 4; ++m)
            #pragma unroll
            for (int n = 0; n < 4; ++n)
                acc[m][n] = __builtin_amdgcn_mfma_f32_16x16x32_bf16(av[m], bw[n], acc[m][n], 0,0,0);
    }
    {
        float bo[4];
        #pragma unroll
        for (int n = 0; n < 4; ++n) bo[n] = out_b[n*16 + l4];
        #pragma unroll
        for (int m = 0; m < 4; ++m)
            #pragma unroll
            for (int n = 0; n < 4; ++n)
                #pragma unroll
                for (int r = 0; r < 4; ++r)
                    acc[m][n][r] += bo[n];
    }
    WSYNC();
    #pragma unroll
    for (int m = 0; m < 4; ++m)
        #pragma unroll
        for (int n = 0; n < 4; ++n)
            #pragma unroll
            for (int r = 0; r < 4; ++r)
                Wp[(m*16 + g4*4 + r)*72 + n*16 + l4] = bfr(acc[m][n][r]);
    __syncthreads();

    // ---------------- P12: cooperative coalesced store (nontemporal) ----------------
    {
        float* obase = out + (bb*64)*HWSZ + (ph*8)*256 + strip*32;
        const unsigned short* lsrc = bufS + lp*PSTR + (ty*8 + lpx)*72;
        #pragma unroll 1
        for (int c8 = 0; c8 < 8; ++c8) {
            u4v v = *(const u4v*)(lsrc + c8*8);
            #pragma unroll
            for (int j = 0; j < 4; ++j) {
                int c = c8*8 + 2*j;
                __builtin_nontemporal_store(bl(v[j]), obase + c*HWSZ + yx);
                __builtin_nontemporal_store(bh(v[j]), obase + (c+1)*HWSZ + yx);
            }
        }
    }
}

extern "C" void kernel_launch(void* const* d_in, const int* in_sizes, int n_in,
                              void* d_out, int out_size, void* d_ws, size_t ws_size,
                              hipStream_t stream) {
    const float* p[35];
    for (int i = 0; i < 35; ++i) p[i] = (const float*)d_in[i];
    unsigned short* ws = (unsigned short*)d_ws;
    float* wsf = (float*)ws + 8192;

    prep_w<<<64, 256, 0, stream>>>(p[1], p[3], p[21], p[23], p[27], p[34], ws);
    prep_t<<<7, 256, 0, stream>>>(p[7], p[9], p[13], p[28], p[15], wsf);

    const int B = in_sizes[0] / (64 * 256 * 256);   // = 4
    dim3 grid(B * 32 * 8), block(256);
    gmlp_fused<<<grid, block, 0, stream>>>(
        p[0],  p[2],  p[4],  p[5],  p[6],  p[8],
        p[10], p[11], p[12], p[14],
        p[16], p[17], p[18], p[19], p[20],
        p[22], p[24], p[25], p[26],
        p[29], p[30], p[31], p[32], p[33],
        ws, (float*)d_out);
}

// Round 5
// 96.724 us; speedup vs baseline: 7.5893x; 1.1712x over previous
//
#include <hip/hip_runtime.h>
#include <math.h>

#define HWSZ 65536
#define EPSF 1e-5f
#define PSTR 4680   // shorts per patch LDS region: 65 rows * 72 (row 64 = zeros)

typedef __attribute__((ext_vector_type(8))) short bf8v;
typedef __attribute__((ext_vector_type(4))) float f4v;
typedef __attribute__((ext_vector_type(4))) unsigned int u4v;
typedef unsigned int uint32;

// bf16 ws offsets (shorts)
#define W_HID_OFF   0
#define W_X1_OFF    4096
#define W_PROJ_OFF  8192
#define W_OUT_OFF   10240
#define W_DWB0_OFF  14336
#define W_DWB2_OFF  15360
// f32 ws region starts at float index 8192
#define F_DWT   0      // dwT[k*64+c]     = xcnn_dw_w[c*9+k]      (576)
#define F_CI1T  576    // ci_w1T[c*8+m]   = ci_w1[m*64+c]         (512)
#define F_CI2T  1088   // ci_w2T[m*32+o]  = ci_w2[o*8+m]          (256)
#define F_IW1T  1344   // idw_w1T[c*8+m]  = idw_w1[m*32+c]        (256)
#define F_SI1T  1600   // si_w1T[c*4+m]   = si_w1[m*32+c]         (128)

__device__ __forceinline__ float sigm(float v){ return 1.0f/(1.0f+expf(-v)); }
__device__ __forceinline__ float bl(uint32 u){ return __uint_as_float(u<<16); }
__device__ __forceinline__ float bh(uint32 u){ return __uint_as_float(u & 0xffff0000u); }
__device__ __forceinline__ uint32 pk2(float a, float b){
  uint32 r; asm("v_cvt_pk_bf16_f32 %0, %1, %2" : "=v"(r) : "v"(a), "v"(b)); return r;
}
__device__ __forceinline__ unsigned short bfr(float x){
  uint32 u = __float_as_uint(x); u += 0x7fffu + ((u>>16)&1u); return (unsigned short)(u>>16);
}
__device__ __forceinline__ float rcp_f(float x){ float r; asm("v_rcp_f32 %0, %1" : "=v"(r) : "v"(x)); return r; }
__device__ __forceinline__ float exp2_f(float x){ float r; asm("v_exp_f32 %0, %1" : "=v"(r) : "v"(x)); return r; }

// exact-enough gelu: erf via Abramowitz-Stegun 7.1.26 (|err| < 1.5e-7), branchless
__device__ __attribute__((noinline)) f4v gelu4(f4v v){
  f4v r;
  #pragma unroll
  for (int i=0;i<4;++i){
    float x  = v[i];
    float z  = fabsf(x) * 0.7071067811865476f;
    float t  = rcp_f(fmaf(0.3275911f, z, 1.0f));
    float p  = t*fmaf(t, fmaf(t, fmaf(t, fmaf(t, 1.061405429f, -1.453152027f),
                       1.421413741f), -0.284496736f), 0.254829592f);
    float ex = exp2_f(-(z*z)*1.4426950408889634f);     // e^{-z^2}
    float er = fmaf(-p, ex, 1.0f);
    float s  = copysignf(er, x);
    float hx = 0.5f*x;
    r[i] = fmaf(hx, s, hx);
  }
  return r;
}

// wave-local LDS fence (our patch region is single-wave between real barriers)
#define WSYNC() asm volatile("s_waitcnt lgkmcnt(0)" ::: "memory")

__global__ void prep_w(const float* __restrict__ a0, const float* __restrict__ a1,
                       const float* __restrict__ a2, const float* __restrict__ a3,
                       const float* __restrict__ a4, const float* __restrict__ a5,
                       unsigned short* __restrict__ ws){
  int i = blockIdx.x*256 + threadIdx.x;
  if (i >= 16384) return;
  float v;
  if      (i < 4096)  v = a0[i];
  else if (i < 8192)  v = a1[i-4096];
  else if (i < 10240) v = a2[i-8192];
  else if (i < 14336) v = a3[i-10240];
  else if (i < 15360) v = a4[i-14336];
  else                v = a5[i-15360];
  ws[i] = bfr(v);
}

__global__ void prep_t(const float* __restrict__ dw, const float* __restrict__ ci1,
                       const float* __restrict__ ci2, const float* __restrict__ iw1,
                       const float* __restrict__ sw1, float* __restrict__ wf){
  int i = blockIdx.x*256 + threadIdx.x;
  if (i >= 1728) return;
  float v;
  if (i < 576)        { int k=i/64, c=i%64;            v = dw[c*9+k]; }
  else if (i < 1088)  { int j=i-576,  c=j/8, m=j%8;    v = ci1[m*64+c]; }
  else if (i < 1344)  { int j=i-1088, m=j/32, o=j%32;  v = ci2[o*8+m]; }
  else if (i < 1600)  { int j=i-1344, c=j/8, m=j%8;    v = iw1[m*32+c]; }
  else                { int j=i-1600, c=j/4, m=j%4;    v = sw1[m*32+c]; }
  wf[i] = v;
}

__global__ __launch_bounds__(256, 4)
void gmlp_fused(const float* __restrict__ x,
                const float* __restrict__ b_hid,
                const float* __restrict__ xcnn_b1,
                const float* __restrict__ xcnn_ln_w, const float* __restrict__ xcnn_ln_b,
                const float* __restrict__ xcnn_dw_b,
                const float* __restrict__ ci_b1,
                const float* __restrict__ ci_ln_w, const float* __restrict__ ci_ln_b,
                const float* __restrict__ ci_b2,
                const float* __restrict__ si_b1,
                const float* __restrict__ si_ln_w, const float* __restrict__ si_ln_b,
                const float* __restrict__ si_w2,   const float* __restrict__ si_b2,
                const float* __restrict__ proj_b,
                const float* __restrict__ out_b,
                const float* __restrict__ sgu_ln_w, const float* __restrict__ sgu_ln_b,
                const float* __restrict__ idw_b1,
                const float* __restrict__ idw_bn_w, const float* __restrict__ idw_bn_b,
                const float* __restrict__ idw_w2,  const float* __restrict__ idw_b2,
                const unsigned short* __restrict__ wsw,
                float* __restrict__ out)
{
    __shared__ __align__(16) unsigned short bufS[4*PSTR];
    __shared__ __align__(16) float segate_s[4][32];

    const float* wf = (const float*)wsw + 8192;

    const int tx  = threadIdx.x;
    const int wid = tx >> 6;
    const int t   = tx & 63;
    const int l4  = t & 15, g4 = t >> 4;
    const int py  = t >> 3,  px = t & 7;

    const int bid   = blockIdx.x;     // grid = B * 32 * 8
    const int strip = bid & 7;
    const int ph    = (bid >> 3) & 31;
    const int bb    = bid >> 8;

    unsigned short* Wp = bufS + wid*PSTR;

    const int ty  = tx >> 5;
    const int txx = tx & 31;
    const int lp  = txx >> 3;
    const int lpx = txx & 7;
    const int yx  = ty*256 + txx;
    const float* xbase = x + (bb*64)*HWSZ + (ph*8)*256 + strip*32;
    unsigned short* ldst = bufS + lp*PSTR + (ty*8 + lpx)*72;

    // ---------------- P1: cooperative coalesced load + zero-row init ----------------
    #pragma unroll 1
    for (int c8 = 0; c8 < 8; ++c8) {
        u4v w;
        #pragma unroll
        for (int j = 0; j < 4; ++j) {
            int c = c8*8 + 2*j;
            float a = __builtin_nontemporal_load(xbase + c*HWSZ + yx);
            float b = __builtin_nontemporal_load(xbase + (c+1)*HWSZ + yx);
            w[j] = pk2(a, b);
        }
        *(u4v*)(ldst + c8*8) = w;
    }
    if (t < 9) *(u4v*)(Wp + 64*72 + t*8) = (u4v){0,0,0,0};   // row 64 = zeros
    __syncthreads();

    // ---------------- P2: hidden GEMM + bias + gelu ----------------
    f4v acc[4][4];
    #pragma unroll
    for (int m = 0; m < 4; ++m)
        #pragma unroll
        for (int n = 0; n < 4; ++n)
            acc[m][n] = (f4v){0.f,0.f,0.f,0.f};
    #pragma unroll 1
    for (int s = 0; s < 2; ++s) {
        bf8v bw[4]; bf8v av[4];
        #pragma unroll
        for (int n = 0; n < 4; ++n) bw[n] = *(const bf8v*)(wsw + W_HID_OFF + (n*16+l4)*64 + s*32 + g4*8);
        #pragma unroll
        for (int m = 0; m < 4; ++m) av[m] = *(const bf8v*)(Wp + (m*16 + l4)*72 + s*32 + g4*8);
        #pragma unroll
        for (int m = 0; m < 4; ++m)
            #pragma unroll
            for (int n = 0; n < 4; ++n)
                acc[m][n] = __builtin_amdgcn_mfma_f32_16x16x32_bf16(av[m], bw[n], acc[m][n], 0,0,0);
    }
    {
        float bhid[4];
        #pragma unroll
        for (int n = 0; n < 4; ++n) bhid[n] = b_hid[n*16 + l4];
        #pragma unroll
        for (int m = 0; m < 4; ++m)
            #pragma unroll
            for (int n = 0; n < 4; ++n) {
                f4v q;
                #pragma unroll
                for (int r = 0; r < 4; ++r) q[r] = acc[m][n][r] + bhid[n];
                acc[m][n] = gelu4(q);
            }
    }
    WSYNC();
    #pragma unroll
    for (int m = 0; m < 4; ++m)
        #pragma unroll
        for (int n = 0; n < 4; ++n)
            #pragma unroll
            for (int r = 0; r < 4; ++r)
                Wp[(m*16 + g4*4 + r)*72 + n*16 + l4] = bfr(acc[m][n][r]);
    WSYNC();

    uint32 hidpk[32];   // res = [0..15], gate = [16..31]
    #pragma unroll
    for (int q8 = 0; q8 < 8; ++q8) {
        u4v v = *(const u4v*)(Wp + t*72 + q8*8);
        #pragma unroll
        for (int j = 0; j < 4; ++j) hidpk[q8*4 + j] = v[j];
    }

    // ---------------- P3: xcnn GEMM + bias, per-pixel LN (LDS 3-pass) ----------------
    #pragma unroll
    for (int m = 0; m < 4; ++m)
        #pragma unroll
        for (int n = 0; n < 4; ++n)
            acc[m][n] = (f4v){0.f,0.f,0.f,0.f};
    #pragma unroll 1
    for (int s = 0; s < 2; ++s) {
        bf8v bw[4]; bf8v av[4];
        #pragma unroll
        for (int n = 0; n < 4; ++n) bw[n] = *(const bf8v*)(wsw + W_X1_OFF + (n*16+l4)*64 + s*32 + g4*8);
        #pragma unroll
        for (int m = 0; m < 4; ++m) av[m] = *(const bf8v*)(Wp + (m*16 + l4)*72 + s*32 + g4*8);
        #pragma unroll
        for (int m = 0; m < 4; ++m)
            #pragma unroll
            for (int n = 0; n < 4; ++n)
                acc[m][n] = __builtin_amdgcn_mfma_f32_16x16x32_bf16(av[m], bw[n], acc[m][n], 0,0,0);
    }
    {
        float bx[4];
        #pragma unroll
        for (int n = 0; n < 4; ++n) bx[n] = xcnn_b1[n*16 + l4];
        #pragma unroll
        for (int m = 0; m < 4; ++m)
            #pragma unroll
            for (int n = 0; n < 4; ++n)
                #pragma unroll
                for (int r = 0; r < 4; ++r)
                    acc[m][n][r] += bx[n];
    }
    WSYNC();
    #pragma unroll
    for (int m = 0; m < 4; ++m)
        #pragma unroll
        for (int n = 0; n < 4; ++n)
            #pragma unroll
            for (int r = 0; r < 4; ++r)
                Wp[(m*16 + g4*4 + r)*72 + n*16 + l4] = bfr(acc[m][n][r]);
    WSYNC();
    {   // LN over 64 channels, 3 rolled passes over own row
        float s = 0.f;
        #pragma unroll 1
        for (int q8 = 0; q8 < 8; ++q8) {
            u4v v = *(const u4v*)(Wp + t*72 + q8*8);
            #pragma unroll
            for (int j = 0; j < 4; ++j) s += bl(v[j]) + bh(v[j]);
        }
        float mu = s * (1.f/64.f);
        float s2 = 0.f;
        #pragma unroll 1
        for (int q8 = 0; q8 < 8; ++q8) {
            u4v v = *(const u4v*)(Wp + t*72 + q8*8);
            #pragma unroll
            for (int j = 0; j < 4; ++j) {
                float d0 = bl(v[j]) - mu, d1 = bh(v[j]) - mu;
                s2 = fmaf(d0, d0, fmaf(d1, d1, s2));
            }
        }
        float rstd = rsqrtf(s2*(1.f/64.f) + EPSF);
        #pragma unroll 1
        for (int q8 = 0; q8 < 8; ++q8) {
            u4v v = *(const u4v*)(Wp + t*72 + q8*8);
            u4v w;
            #pragma unroll
            for (int j = 0; j < 4; ++j) {
                int c = q8*8 + 2*j;
                float a = (bl(v[j]) - mu)*rstd*xcnn_ln_w[c]   + xcnn_ln_b[c];
                float b = (bh(v[j]) - mu)*rstd*xcnn_ln_w[c+1] + xcnn_ln_b[c+1];
                w[j] = pk2(a, b);
            }
            *(u4v*)(Wp + t*72 + q8*8) = w;
        }
    }
    WSYNC();

    // ---------------- P4: depthwise 3x3 + gelu (zero-row border, two halves) ----------------
    #pragma unroll 1
    for (int h = 0; h < 2; ++h) {
        float xh[32];
        #pragma unroll
        for (int o = 0; o < 32; ++o) xh[o] = xcnn_dw_b[h*32 + o];
        #pragma unroll 1
        for (int ki = 0; ki < 3; ++ki) {
            #pragma unroll 1
            for (int kj = 0; kj < 3; ++kj) {
                int rr = py + ki - 1, cc = px + kj - 1;
                bool val = ((unsigned)rr < 8u) && ((unsigned)cc < 8u);
                int pnn = val ? rr*8 + cc : 64;     // row 64 = zeros
                const unsigned short* rp = Wp + pnn*72 + h*32;
                const float* wp = wf + F_DWT + (ki*3+kj)*64 + h*32;
                #pragma unroll
                for (int c8 = 0; c8 < 4; ++c8) {
                    u4v v = *(const u4v*)(rp + c8*8);
                    #pragma unroll
                    for (int j = 0; j < 4; ++j) {
                        int c = c8*8 + 2*j;
                        xh[c]   = fmaf(bl(v[j]), wp[c],   xh[c]);
                        xh[c+1] = fmaf(bh(v[j]), wp[c+1], xh[c+1]);
                    }
                }
            }
        }
        #pragma unroll
        for (int g = 0; g < 8; ++g) {
            f4v q = (f4v){xh[4*g], xh[4*g+1], xh[4*g+2], xh[4*g+3]};
            q = gelu4(q);
            xh[4*g]=q[0]; xh[4*g+1]=q[1]; xh[4*g+2]=q[2]; xh[4*g+3]=q[3];
        }
        WSYNC();
        #pragma unroll
        for (int c8 = 0; c8 < 4; ++c8) {
            u4v w;
            #pragma unroll
            for (int j = 0; j < 4; ++j) w[j] = pk2(xh[c8*8+2*j], xh[c8*8+2*j+1]);
            *(u4v*)(Wp + t*72 + h*32 + c8*8) = w;
        }
    }
    WSYNC();

    // ---------------- P4.5: channel mean (lane = channel) + proj GEMM ----------------
    float pc;
    {
        float ps = 0.f;
        #pragma unroll 1
        for (int p8 = 0; p8 < 8; ++p8) {
            #pragma unroll
            for (int q = 0; q < 8; ++q) ps += bl((uint32)Wp[(p8*8+q)*72 + t]);
        }
        pc = ps * (1.f/64.f);
    }
    f4v accp[4][2];
    #pragma unroll
    for (int m = 0; m < 4; ++m) { accp[m][0] = (f4v){0.f,0.f,0.f,0.f}; accp[m][1] = (f4v){0.f,0.f,0.f,0.f}; }
    #pragma unroll 1
    for (int s = 0; s < 2; ++s) {
        bf8v bw[2]; bf8v av[4];
        #pragma unroll
        for (int n = 0; n < 2; ++n) bw[n] = *(const bf8v*)(wsw + W_PROJ_OFF + (n*16+l4)*64 + s*32 + g4*8);
        #pragma unroll
        for (int m = 0; m < 4; ++m) av[m] = *(const bf8v*)(Wp + (m*16 + l4)*72 + s*32 + g4*8);
        #pragma unroll
        for (int m = 0; m < 4; ++m)
            #pragma unroll
            for (int n = 0; n < 2; ++n)
                accp[m][n] = __builtin_amdgcn_mfma_f32_16x16x32_bf16(av[m], bw[n], accp[m][n], 0,0,0);
    }
    {
        float bp0 = proj_b[l4], bp1 = proj_b[16 + l4];
        #pragma unroll
        for (int m = 0; m < 4; ++m)
            #pragma unroll
            for (int r = 0; r < 4; ++r) { accp[m][0][r] += bp0; accp[m][1][r] += bp1; }
    }
    WSYNC();
    #pragma unroll
    for (int m = 0; m < 4; ++m)
        #pragma unroll
        for (int n = 0; n < 2; ++n)
            #pragma unroll
            for (int r = 0; r < 4; ++r)
                Wp[(m*16 + g4*4 + r)*72 + n*16 + l4] = bfr(accp[m][n][r]);
    WSYNC();
    uint32 xppk[16];
    #pragma unroll
    for (int q8 = 0; q8 < 4; ++q8) {
        u4v v = *(const u4v*)(Wp + t*72 + q8*8);
        #pragma unroll
        for (int j = 0; j < 4; ++j) xppk[q8*4 + j] = v[j];
    }

    // ---------------- P5: SE gate (distributed matvec via shfl butterfly) ----------------
    {
        float pt[8];
        {
            f4v wa = *(const f4v*)(wf + F_CI1T + t*8);
            f4v wb = *(const f4v*)(wf + F_CI1T + t*8 + 4);
            #pragma unroll
            for (int m = 0; m < 4; ++m) { pt[m] = wa[m]*pc; pt[4+m] = wb[m]*pc; }
        }
        #pragma unroll
        for (int st = 1; st < 64; st <<= 1)
            #pragma unroll
            for (int m = 0; m < 8; ++m) pt[m] += __shfl_xor(pt[m], st, 64);
        float t8[8];
        #pragma unroll
        for (int m = 0; m < 8; ++m) t8[m] = pt[m] + ci_b1[m];
        float s = 0.f;
        #pragma unroll
        for (int m = 0; m < 8; ++m) s += t8[m];
        float mu = s * 0.125f;
        float q2 = 0.f;
        #pragma unroll
        for (int m = 0; m < 8; ++m) { float d = t8[m]-mu; q2 = fmaf(d,d,q2); }
        float rstd = rsqrtf(q2*0.125f + EPSF);
        #pragma unroll
        for (int m = 0; m < 8; ++m) t8[m] = (t8[m]-mu)*rstd*ci_ln_w[m] + ci_ln_b[m];
        f4v qa = gelu4((f4v){t8[0],t8[1],t8[2],t8[3]});
        f4v qb = gelu4((f4v){t8[4],t8[5],t8[6],t8[7]});
        t8[0]=qa[0]; t8[1]=qa[1]; t8[2]=qa[2]; t8[3]=qa[3];
        t8[4]=qb[0]; t8[5]=qb[1]; t8[6]=qb[2]; t8[7]=qb[3];
        if (t < 32) {
            float a = ci_b2[t];
            #pragma unroll
            for (int m = 0; m < 8; ++m) a = fmaf(wf[F_CI2T + m*32 + t], t8[m], a);
            segate_s[wid][t] = sigm(a);
        }
    }
    WSYNC();
    float sg[32];
    #pragma unroll
    for (int g = 0; g < 8; ++g) {
        f4v e = *(const f4v*)&segate_s[wid][g*4];
        #pragma unroll
        for (int r = 0; r < 4; ++r) {
            int o = g*4 + r;
            uint32 pkv = hidpk[16 + o/2];
            float gv = (o & 1) ? bh(pkv) : bl(pkv);
            sg[o] = gv * e[r];
        }
    }
    {   // SGU LayerNorm over 32
        float s = 0.f;
        #pragma unroll
        for (int o = 0; o < 32; ++o) s += sg[o];
        float mu = s * (1.f/32.f);
        float q2 = 0.f;
        #pragma unroll
        for (int o = 0; o < 32; ++o) { float d = sg[o]-mu; q2 = fmaf(d,d,q2); }
        float rstd = rsqrtf(q2*(1.f/32.f) + EPSF);
        #pragma unroll
        for (int o = 0; o < 32; ++o) sg[o] = (sg[o]-mu)*rstd*sgu_ln_w[o] + sgu_ln_b[o];
    }
    WSYNC();
    #pragma unroll
    for (int c8 = 0; c8 < 4; ++c8) {
        u4v w;
        #pragma unroll
        for (int j = 0; j < 4; ++j) w[j] = pk2(sg[c8*8+2*j], sg[c8*8+2*j+1]);
        *(u4v*)(Wp + t*72 + c8*8) = w;
    }
    WSYNC();

    // ---------------- P7: dwb_w0 GEMM -> write g1 TRANSPOSED (Gt, cols 32..63) ----------------
    // Gt[c][q]: block s=q>>5 at row s*32+c, col 32+(q&31)
    {
        f4v accg[4][2];
        #pragma unroll
        for (int m = 0; m < 4; ++m) { accg[m][0] = (f4v){0.f,0.f,0.f,0.f}; accg[m][1] = (f4v){0.f,0.f,0.f,0.f}; }
        bf8v bw[2]; bf8v av[4];
        #pragma unroll
        for (int n = 0; n < 2; ++n) bw[n] = *(const bf8v*)(wsw + W_DWB0_OFF + (n*16+l4)*32 + g4*8);
        #pragma unroll
        for (int m = 0; m < 4; ++m) av[m] = *(const bf8v*)(Wp + (m*16 + l4)*72 + g4*8);
        #pragma unroll
        for (int m = 0; m < 4; ++m)
            #pragma unroll
            for (int n = 0; n < 2; ++n)
                accg[m][n] = __builtin_amdgcn_mfma_f32_16x16x32_bf16(av[m], bw[n], accg[m][n], 0,0,0);
        WSYNC();
        #pragma unroll
        for (int m = 0; m < 4; ++m)
            #pragma unroll
            for (int n = 0; n < 2; ++n)
                #pragma unroll
                for (int r = 0; r < 4; ++r) {
                    int q = m*16 + g4*4 + r;
                    Wp[((q>>5)*32 + n*16 + l4)*72 + 32 + (q & 31)] = bfr(accg[m][n][r]);
                }
    }
    WSYNC();

    // ---------------- P8: idw kernel gen + dynamic 7x7 via MFMA (K-split M build) ----------------
    float t8b[8];
    #pragma unroll
    for (int m = 0; m < 8; ++m) t8b[m] = idw_b1[m];
    #pragma unroll 1
    for (int c = 0; c < 32; ++c) {      // g1 row t = Gt column t
        float gv = bl((uint32)Wp[((t>>5)*32 + c)*72 + 32 + (t & 31)]);
        #pragma unroll
        for (int m = 0; m < 8; ++m) t8b[m] = fmaf(wf[F_IW1T + c*8 + m], gv, t8b[m]);
    }
    #pragma unroll
    for (int m = 0; m < 8; ++m)
        t8b[m] = fmaxf(t8b[m]*(idw_bn_w[m]*0.9999950000374997f) + idw_bn_b[m], 0.f);

    f4v accd[4][2];
    #pragma unroll
    for (int m = 0; m < 4; ++m) { accd[m][0] = (f4v){0.f,0.f,0.f,0.f}; accd[m][1] = (f4v){0.f,0.f,0.f,0.f}; }
    #pragma unroll 1
    for (int s = 0; s < 2; ++s) {
        WSYNC();
        // zero own M row (cols 0..31)
        #pragma unroll
        for (int i = 0; i < 4; ++i) *(u4v*)(Wp + t*72 + i*8) = (u4v){0,0,0,0};
        // scatter own taps of K-block s: M[t][q] = wdyn[t][k], q = neighbor(t,k)
        #pragma unroll 1
        for (int ki = 0; ki < 7; ++ki) {
            int rr = py + ki - 3;
            #pragma unroll 1
            for (int kj = 0; kj < 7; ++kj) {
                int cc = px + kj - 3;
                int k  = ki*7 + kj;
                float wk = idw_b2[k];
                #pragma unroll
                for (int m = 0; m < 8; ++m) wk = fmaf(idw_w2[k*8 + m], t8b[m], wk);
                int q = rr*8 + cc;
                if (((unsigned)rr < 8u) && ((unsigned)cc < 8u) && ((q >> 5) == s))
                    Wp[t*72 + (q & 31)] = bfr(wk);
            }
        }
        WSYNC();
        // GEMM K-step s: A = M (rows p, cols 0..31), B = Gt block s
        bf8v aM[4], bG[2];
        #pragma unroll
        for (int m = 0; m < 4; ++m) aM[m] = *(const bf8v*)(Wp + (m*16 + l4)*72 + g4*8);
        #pragma unroll
        for (int n = 0; n < 2; ++n) bG[n] = *(const bf8v*)(Wp + (s*32 + n*16 + l4)*72 + 32 + g4*8);
        #pragma unroll
        for (int m = 0; m < 4; ++m)
            #pragma unroll
            for (int n = 0; n < 2; ++n)
                accd[m][n] = __builtin_amdgcn_mfma_f32_16x16x32_bf16(aM[m], bG[n], accd[m][n], 0,0,0);
    }
    WSYNC();
    #pragma unroll
    for (int m = 0; m < 4; ++m)
        #pragma unroll
        for (int n = 0; n < 2; ++n)
            #pragma unroll
            for (int r = 0; r < 4; ++r)
                Wp[(m*16 + g4*4 + r)*72 + n*16 + l4] = bfr(accd[m][n][r]);
    WSYNC();

    // ---------------- P9: dwb_w2 GEMM -> sgu = g2 * res ----------------
    {
        f4v accg[4][2];
        #pragma unroll
        for (int m = 0; m < 4; ++m) { accg[m][0] = (f4v){0.f,0.f,0.f,0.f}; accg[m][1] = (f4v){0.f,0.f,0.f,0.f}; }
        bf8v bw[2]; bf8v av[4];
        #pragma unroll
        for (int n = 0; n < 2; ++n) bw[n] = *(const bf8v*)(wsw + W_DWB2_OFF + (n*16+l4)*32 + g4*8);
        #pragma unroll
        for (int m = 0; m < 4; ++m) av[m] = *(const bf8v*)(Wp + (m*16 + l4)*72 + g4*8);
        #pragma unroll
        for (int m = 0; m < 4; ++m)
            #pragma unroll
            for (int n = 0; n < 2; ++n)
                accg[m][n] = __builtin_amdgcn_mfma_f32_16x16x32_bf16(av[m], bw[n], accg[m][n], 0,0,0);
        WSYNC();
        #pragma unroll
        for (int m = 0; m < 4; ++m)
            #pragma unroll
            for (int n = 0; n < 2; ++n)
                #pragma unroll
                for (int r = 0; r < 4; ++r)
                    Wp[(m*16 + g4*4 + r)*72 + n*16 + l4] = bfr(accg[m][n][r]);
        WSYNC();
    }
    float sgu[32];
    #pragma unroll
    for (int q8 = 0; q8 < 4; ++q8) {
        u4v v = *(const u4v*)(Wp + t*72 + q8*8);
        #pragma unroll
        for (int j = 0; j < 4; ++j) {
            int q = q8*4 + j;
            sgu[2*q]   = bl(v[j]) * bl(hidpk[q]);
            sgu[2*q+1] = bh(v[j]) * bh(hidpk[q]);
        }
    }
    WSYNC();

    // ---------------- P10: stage sgu (cols 32..63), si gate, stage xp*siv ----------------
    #pragma unroll
    for (int c8 = 0; c8 < 4; ++c8) {
        u4v w;
        #pragma unroll
        for (int j = 0; j < 4; ++j) w[j] = pk2(sgu[c8*8+2*j], sgu[c8*8+2*j+1]);
        *(u4v*)(Wp + t*72 + 32 + c8*8) = w;
    }
    WSYNC();
    float siv;
    {
        float s1[4];
        #pragma unroll
        for (int m = 0; m < 4; ++m) s1[m] = si_b1[m];
        #pragma unroll 1
        for (int c8 = 0; c8 < 4; ++c8) {
            u4v v = *(const u4v*)(Wp + t*72 + 32 + c8*8);
            #pragma unroll
            for (int j = 0; j < 4; ++j) {
                int c = c8*8 + 2*j;
                float a0 = bl(v[j]), a1 = bh(v[j]);
                #pragma unroll
                for (int m = 0; m < 4; ++m) {
                    s1[m] = fmaf(wf[F_SI1T + c*4 + m],     a0, s1[m]);
                    s1[m] = fmaf(wf[F_SI1T + (c+1)*4 + m], a1, s1[m]);
                }
            }
        }
        float s = s1[0]+s1[1]+s1[2]+s1[3];
        float mu = s * 0.25f;
        float q2 = 0.f;
        #pragma unroll
        for (int m = 0; m < 4; ++m) { float d = s1[m]-mu; q2 = fmaf(d,d,q2); }
        float rstd = rsqrtf(q2*0.25f + EPSF);
        f4v q;
        #pragma unroll
        for (int m = 0; m < 4; ++m) q[m] = (s1[m]-mu)*rstd*si_ln_w[m] + si_ln_b[m];
        q = gelu4(q);
        float a = si_b2[0];
        #pragma unroll
        for (int m = 0; m < 4; ++m) a = fmaf(si_w2[m], q[m], a);
        siv = sigm(a);
    }
    #pragma unroll
    for (int c8 = 0; c8 < 4; ++c8) {
        u4v w;
        #pragma unroll
        for (int j = 0; j < 4; ++j) {
            int q = c8*4 + j;
            w[j] = pk2(bl(xppk[q])*siv, bh(xppk[q])*siv);
        }
        *(u4v*)(Wp + t*72 + c8*8) = w;
    }
    WSYNC();

    // ---------------- P11: out GEMM + bias ----------------
    #pragma unroll
    for (int m = 0; m < 4; ++m)
        #pragma unroll
        for (int n = 0; n < 4; ++n)
            acc[m][n] = (f4v){0.f,0.f,0.f,0.f};
    #pragma unroll 1
    for (int s = 0; s < 2; ++s) {
        bf8v bw[4]; bf8v av[4];
        #pragma unroll
        for (int n = 0; n < 4; ++n) bw[n] = *(const bf8v*)(wsw + W_OUT_OFF + (n*16+l4)*64 + s*32 + g4*8);
        #pragma unroll
        for (int m = 0; m < 4; ++m) av[m] = *(const bf8v*)(Wp + (m*16 + l4)*72 + s*32 + g4*8);
        #pragma unroll
        for (int m = 0; m < 4; ++m)
            #pragma unroll
            for (int n = 0; n < 4; ++n)
                acc[m][n] = __builtin_amdgcn_mfma_f32_16x16x32_bf16(av[m], bw[n], acc[m][n], 0,0,0);
    }
    {
        float bo[4];
        #pragma unroll
        for (int n = 0; n < 4; ++n) bo[n] = out_b[n*16 + l4];
        #pragma unroll
        for (int m = 0; m < 4; ++m)
            #pragma unroll
            for (int n = 0; n < 4; ++n)
                #pragma unroll
                for (int r = 0; r < 4; ++r)
                    acc[m][n][r] += bo[n];
    }
    WSYNC();
    #pragma unroll
    for (int m = 0; m < 4; ++m)
        #pragma unroll
        for (int n = 0; n < 4; ++n)
            #pragma unroll
            for (int r = 0; r < 4; ++r)
                Wp[(m*16 + g4*4 + r)*72 + n*16 + l4] = bfr(acc[m][n][r]);
    __syncthreads();

    // ---------------- P12: cooperative coalesced store (nontemporal) ----------------
    {
        float* obase = out + (bb*64)*HWSZ + (ph*8)*256 + strip*32;
        const unsigned short* lsrc = bufS + lp*PSTR + (ty*8 + lpx)*72;
        #pragma unroll 1
        for (int c8 = 0; c8 < 8; ++c8) {
            u4v v = *(const u4v*)(lsrc + c8*8);
            #pragma unroll
            for (int j = 0; j < 4; ++j) {
                int c = c8*8 + 2*j;
                __builtin_nontemporal_store(bl(v[j]), obase + c*HWSZ + yx);
                __builtin_nontemporal_store(bh(v[j]), obase + (c+1)*HWSZ + yx);
            }
        }
    }
}

extern "C" void kernel_launch(void* const* d_in, const int* in_sizes, int n_in,
                              void* d_out, int out_size, void* d_ws, size_t ws_size,
                              hipStream_t stream) {
    const float* p[35];
    for (int i = 0; i < 35; ++i) p[i] = (const float*)d_in[i];
    unsigned short* ws = (unsigned short*)d_ws;
    float* wsf = (float*)ws + 8192;

    prep_w<<<64, 256, 0, stream>>>(p[1], p[3], p[21], p[23], p[27], p[34], ws);
    prep_t<<<7, 256, 0, stream>>>(p[7], p[9], p[13], p[28], p[15], wsf);

    const int B = in_sizes[0] / (64 * 256 * 256);   // = 4
    dim3 grid(B * 32 * 8), block(256);
    gmlp_fused<<<grid, block, 0, stream>>>(
        p[0],  p[2],  p[4],  p[5],  p[6],  p[8],
        p[10], p[11], p[12], p[14],
        p[16], p[17], p[18], p[19], p[20],
        p[22], p[24], p[25], p[26],
        p[29], p[30], p[31], p[32], p[33],
        ws, (float*)d_out);
}

// Round 8
// 96.507 us; speedup vs baseline: 7.6064x; 1.0022x over previous
//
#include <hip/hip_runtime.h>
#include <math.h>

#define HWSZ 65536
#define EPSF 1e-5f
#define PSTR 4680   // shorts per patch LDS region: 65 rows * 72 (row 64 = zeros)

typedef __attribute__((ext_vector_type(8))) short bf8v;
typedef __attribute__((ext_vector_type(4))) float f4v;
typedef __attribute__((ext_vector_type(4))) unsigned int u4v;
typedef unsigned int uint32;

// bf16 ws offsets (shorts)
#define W_HID_OFF   0
#define W_X1_OFF    4096
#define W_PROJ_OFF  8192
#define W_OUT_OFF   10240
#define W_DWB0_OFF  14336
#define W_DWB2_OFF  15360
// f32 ws region starts at float index 8192
#define F_DWT   0
#define F_CI1T  576
#define F_CI2T  1088
#define F_IW1T  1344
#define F_SI1T  1600

__device__ __forceinline__ float bl(uint32 u){ return __uint_as_float(u<<16); }
__device__ __forceinline__ float bh(uint32 u){ return __uint_as_float(u & 0xffff0000u); }
__device__ __forceinline__ uint32 pk2(float a, float b){
  uint32 r; asm("v_cvt_pk_bf16_f32 %0, %1, %2" : "=v"(r) : "v"(a), "v"(b)); return r;
}
__device__ __forceinline__ unsigned short bfr(float x){
  uint32 u = __float_as_uint(x); u += 0x7fffu + ((u>>16)&1u); return (unsigned short)(u>>16);
}
__device__ __forceinline__ float rcp_f(float x){ float r; asm("v_rcp_f32 %0, %1" : "=v"(r) : "v"(x)); return r; }
__device__ __forceinline__ float exp2_f(float x){ float r; asm("v_exp_f32 %0, %1" : "=v"(r) : "v"(x)); return r; }
__device__ __forceinline__ float sigm(float v){
  return rcp_f(1.0f + exp2_f(v * -1.4426950408889634f));
}

// exact-enough gelu: erf via Abramowitz-Stegun 7.1.26 (|err| < 1.5e-7), branchless
__device__ __attribute__((noinline)) f4v gelu4(f4v v){
  f4v r;
  #pragma unroll
  for (int i=0;i<4;++i){
    float x  = v[i];
    float z  = fabsf(x) * 0.7071067811865476f;
    float t  = rcp_f(fmaf(0.3275911f, z, 1.0f));
    float p  = t*fmaf(t, fmaf(t, fmaf(t, fmaf(t, 1.061405429f, -1.453152027f),
                       1.421413741f), -0.284496736f), 0.254829592f);
    float ex = exp2_f(-(z*z)*1.4426950408889634f);
    float er = fmaf(-p, ex, 1.0f);
    float s  = copysignf(er, x);
    float hx = 0.5f*x;
    r[i] = fmaf(hx, s, hx);
  }
  return r;
}

// wave-local LDS fence: waits lgkmcnt only (in-flight VMEM loads cross it)
#define WSYNC() asm volatile("s_waitcnt lgkmcnt(0)" ::: "memory")

__global__ void prep_w(const float* __restrict__ a0, const float* __restrict__ a1,
                       const float* __restrict__ a2, const float* __restrict__ a3,
                       const float* __restrict__ a4, const float* __restrict__ a5,
                       unsigned short* __restrict__ ws){
  int i = blockIdx.x*256 + threadIdx.x;
  if (i >= 16384) return;
  float v;
  if      (i < 4096)  v = a0[i];
  else if (i < 8192)  v = a1[i-4096];
  else if (i < 10240) v = a2[i-8192];
  else if (i < 14336) v = a3[i-10240];
  else if (i < 15360) v = a4[i-14336];
  else                v = a5[i-15360];
  ws[i] = bfr(v);
}

__global__ void prep_t(const float* __restrict__ dw, const float* __restrict__ ci1,
                       const float* __restrict__ ci2, const float* __restrict__ iw1,
                       const float* __restrict__ sw1, float* __restrict__ wf){
  int i = blockIdx.x*256 + threadIdx.x;
  if (i >= 1728) return;
  float v;
  if (i < 576)        { int k=i/64, c=i%64;            v = dw[c*9+k]; }
  else if (i < 1088)  { int j=i-576,  c=j/8, m=j%8;    v = ci1[m*64+c]; }
  else if (i < 1344)  { int j=i-1088, m=j/32, o=j%32;  v = ci2[o*8+m]; }
  else if (i < 1600)  { int j=i-1344, c=j/8, m=j%8;    v = iw1[m*32+c]; }
  else                { int j=i-1600, c=j/4, m=j%4;    v = sw1[m*32+c]; }
  wf[i] = v;
}

__global__ __launch_bounds__(256, 4)
void gmlp_fused(const float* __restrict__ x,
                const float* __restrict__ b_hid,
                const float* __restrict__ xcnn_b1,
                const float* __restrict__ xcnn_ln_w, const float* __restrict__ xcnn_ln_b,
                const float* __restrict__ xcnn_dw_b,
                const float* __restrict__ ci_b1,
                const float* __restrict__ ci_ln_w, const float* __restrict__ ci_ln_b,
                const float* __restrict__ ci_b2,
                const float* __restrict__ si_b1,
                const float* __restrict__ si_ln_w, const float* __restrict__ si_ln_b,
                const float* __restrict__ si_w2,   const float* __restrict__ si_b2,
                const float* __restrict__ proj_b,
                const float* __restrict__ out_b,
                const float* __restrict__ sgu_ln_w, const float* __restrict__ sgu_ln_b,
                const float* __restrict__ idw_b1,
                const float* __restrict__ idw_bn_w, const float* __restrict__ idw_bn_b,
                const float* __restrict__ idw_w2,  const float* __restrict__ idw_b2,
                const unsigned short* __restrict__ wsw,
                float* __restrict__ out)
{
    __shared__ __align__(16) unsigned short bufS[4*PSTR];
    __shared__ __align__(16) float segate_s[4][32];

    const float* wf = (const float*)wsw + 8192;

    const int tx  = threadIdx.x;
    const int wid = tx >> 6;
    const int t   = tx & 63;
    const int l4  = t & 15, g4 = t >> 4;
    const int py  = t >> 3,  px = t & 7;

    const int bid   = blockIdx.x;     // grid = B * 32 * 8
    const int strip = bid & 7;
    const int ph    = (bid >> 3) & 31;
    const int bb    = bid >> 8;

    unsigned short* Wp = bufS + wid*PSTR;

    const int ty  = tx >> 5;
    const int txx = tx & 31;
    const int lp  = txx >> 3;
    const int lpx = txx & 7;
    const int yx  = ty*256 + txx;
    const float* xbase = x + (bb*64)*HWSZ + (ph*8)*256 + strip*32;
    unsigned short* ldst = bufS + lp*PSTR + (ty*8 + lpx)*72;

    // ---------------- P1: cooperative coalesced load + zero-row + hidW prefetch ----------------
    #pragma unroll 1
    for (int c8 = 0; c8 < 8; ++c8) {
        u4v w;
        #pragma unroll
        for (int j = 0; j < 4; ++j) {
            int c = c8*8 + 2*j;
            float a = __builtin_nontemporal_load(xbase + c*HWSZ + yx);
            float b = __builtin_nontemporal_load(xbase + (c+1)*HWSZ + yx);
            w[j] = pk2(a, b);
        }
        *(u4v*)(ldst + c8*8) = w;
    }
    if (t < 9) *(u4v*)(Wp + 64*72 + t*8) = (u4v){0,0,0,0};   // row 64 = zeros
    // prefetch hidden weights (consumed in P2; cover = barrier + ds_reads)
    bf8v hidW[8];
    #pragma unroll
    for (int s = 0; s < 2; ++s)
        #pragma unroll
        for (int n = 0; n < 4; ++n)
            hidW[s*4+n] = *(const bf8v*)(wsw + W_HID_OFF + (n*16+l4)*64 + s*32 + g4*8);
    __syncthreads();

    // ---------------- P2: hidden GEMM + bias + gelu ----------------
    f4v acc[4][4];
    #pragma unroll
    for (int m = 0; m < 4; ++m)
        #pragma unroll
        for (int n = 0; n < 4; ++n)
            acc[m][n] = (f4v){0.f,0.f,0.f,0.f};
    {
        bf8v a0[4], a1[4];
        #pragma unroll
        for (int m = 0; m < 4; ++m) a0[m] = *(const bf8v*)(Wp + (m*16 + l4)*72 + g4*8);
        #pragma unroll
        for (int m = 0; m < 4; ++m) a1[m] = *(const bf8v*)(Wp + (m*16 + l4)*72 + 32 + g4*8);
        #pragma unroll
        for (int m = 0; m < 4; ++m)
            #pragma unroll
            for (int n = 0; n < 4; ++n)
                acc[m][n] = __builtin_amdgcn_mfma_f32_16x16x32_bf16(a0[m], hidW[n], acc[m][n], 0,0,0);
        #pragma unroll
        for (int m = 0; m < 4; ++m)
            #pragma unroll
            for (int n = 0; n < 4; ++n)
                acc[m][n] = __builtin_amdgcn_mfma_f32_16x16x32_bf16(a1[m], hidW[4+n], acc[m][n], 0,0,0);
    }
    {
        float bhid[4];
        #pragma unroll
        for (int n = 0; n < 4; ++n) bhid[n] = b_hid[n*16 + l4];
        #pragma unroll
        for (int m = 0; m < 4; ++m)
            #pragma unroll
            for (int n = 0; n < 4; ++n) {
                f4v q;
                #pragma unroll
                for (int r = 0; r < 4; ++r) q[r] = acc[m][n][r] + bhid[n];
                acc[m][n] = gelu4(q);
            }
    }
    // prefetch xcnn weights (consumed in P3)
    bf8v x1W[8];
    #pragma unroll
    for (int s = 0; s < 2; ++s)
        #pragma unroll
        for (int n = 0; n < 4; ++n)
            x1W[s*4+n] = *(const bf8v*)(wsw + W_X1_OFF + (n*16+l4)*64 + s*32 + g4*8);
    WSYNC();
    #pragma unroll
    for (int m = 0; m < 4; ++m)
        #pragma unroll
        for (int n = 0; n < 4; ++n)
            #pragma unroll
            for (int r = 0; r < 4; ++r)
                Wp[(m*16 + g4*4 + r)*72 + n*16 + l4] = bfr(acc[m][n][r]);
    WSYNC();

    uint32 hidpk[32];   // res = [0..15], gate = [16..31]
    #pragma unroll
    for (int q8 = 0; q8 < 8; ++q8) {
        u4v v = *(const u4v*)(Wp + t*72 + q8*8);
        #pragma unroll
        for (int j = 0; j < 4; ++j) hidpk[q8*4 + j] = v[j];
    }

    // ---------------- P3: xcnn GEMM + bias, per-pixel LN (LDS 3-pass) ----------------
    #pragma unroll
    for (int m = 0; m < 4; ++m)
        #pragma unroll
        for (int n = 0; n < 4; ++n)
            acc[m][n] = (f4v){0.f,0.f,0.f,0.f};
    {
        bf8v a0[4], a1[4];
        #pragma unroll
        for (int m = 0; m < 4; ++m) a0[m] = *(const bf8v*)(Wp + (m*16 + l4)*72 + g4*8);
        #pragma unroll
        for (int m = 0; m < 4; ++m) a1[m] = *(const bf8v*)(Wp + (m*16 + l4)*72 + 32 + g4*8);
        #pragma unroll
        for (int m = 0; m < 4; ++m)
            #pragma unroll
            for (int n = 0; n < 4; ++n)
                acc[m][n] = __builtin_amdgcn_mfma_f32_16x16x32_bf16(a0[m], x1W[n], acc[m][n], 0,0,0);
        #pragma unroll
        for (int m = 0; m < 4; ++m)
            #pragma unroll
            for (int n = 0; n < 4; ++n)
                acc[m][n] = __builtin_amdgcn_mfma_f32_16x16x32_bf16(a1[m], x1W[4+n], acc[m][n], 0,0,0);
    }
    {
        float bx[4];
        #pragma unroll
        for (int n = 0; n < 4; ++n) bx[n] = xcnn_b1[n*16 + l4];
        #pragma unroll
        for (int m = 0; m < 4; ++m)
            #pragma unroll
            for (int n = 0; n < 4; ++n)
                #pragma unroll
                for (int r = 0; r < 4; ++r)
                    acc[m][n][r] += bx[n];
    }
    // prefetch proj weights (consumed in P4.5, after the long P4 phase)
    bf8v projW[4];
    #pragma unroll
    for (int s = 0; s < 2; ++s)
        #pragma unroll
        for (int n = 0; n < 2; ++n)
            projW[s*2+n] = *(const bf8v*)(wsw + W_PROJ_OFF + (n*16+l4)*64 + s*32 + g4*8);
    WSYNC();
    #pragma unroll
    for (int m = 0; m < 4; ++m)
        #pragma unroll
        for (int n = 0; n < 4; ++n)
            #pragma unroll
            for (int r = 0; r < 4; ++r)
                Wp[(m*16 + g4*4 + r)*72 + n*16 + l4] = bfr(acc[m][n][r]);
    WSYNC();
    {   // LN over 64 channels, 3 rolled passes over own row
        float s = 0.f;
        #pragma unroll 1
        for (int q8 = 0; q8 < 8; ++q8) {
            u4v v = *(const u4v*)(Wp + t*72 + q8*8);
            #pragma unroll
            for (int j = 0; j < 4; ++j) s += bl(v[j]) + bh(v[j]);
        }
        float mu = s * (1.f/64.f);
        float s2 = 0.f;
        #pragma unroll 1
        for (int q8 = 0; q8 < 8; ++q8) {
            u4v v = *(const u4v*)(Wp + t*72 + q8*8);
            #pragma unroll
            for (int j = 0; j < 4; ++j) {
                float d0 = bl(v[j]) - mu, d1 = bh(v[j]) - mu;
                s2 = fmaf(d0, d0, fmaf(d1, d1, s2));
            }
        }
        float rstd = rsqrtf(s2*(1.f/64.f) + EPSF);
        #pragma unroll 1
        for (int q8 = 0; q8 < 8; ++q8) {
            u4v v = *(const u4v*)(Wp + t*72 + q8*8);
            u4v w;
            #pragma unroll
            for (int j = 0; j < 4; ++j) {
                int c = q8*8 + 2*j;
                float a = (bl(v[j]) - mu)*rstd*xcnn_ln_w[c]   + xcnn_ln_b[c];
                float b = (bh(v[j]) - mu)*rstd*xcnn_ln_w[c+1] + xcnn_ln_b[c+1];
                w[j] = pk2(a, b);
            }
            *(u4v*)(Wp + t*72 + q8*8) = w;
        }
    }
    WSYNC();

    // ---------------- P4: depthwise 3x3 + gelu (zero-row border, two halves) ----------------
    #pragma unroll 1
    for (int h = 0; h < 2; ++h) {
        float xh[32];
        #pragma unroll
        for (int o = 0; o < 32; ++o) xh[o] = xcnn_dw_b[h*32 + o];
        #pragma unroll 1
        for (int ki = 0; ki < 3; ++ki) {
            #pragma unroll 1
            for (int kj = 0; kj < 3; ++kj) {
                int rr = py + ki - 1, cc = px + kj - 1;
                bool val = ((unsigned)rr < 8u) && ((unsigned)cc < 8u);
                int pnn = val ? rr*8 + cc : 64;
                const unsigned short* rp = Wp + pnn*72 + h*32;
                const float* wp = wf + F_DWT + (ki*3+kj)*64 + h*32;
                #pragma unroll
                for (int c8 = 0; c8 < 4; ++c8) {
                    u4v v = *(const u4v*)(rp + c8*8);
                    #pragma unroll
                    for (int j = 0; j < 4; ++j) {
                        int c = c8*8 + 2*j;
                        xh[c]   = fmaf(bl(v[j]), wp[c],   xh[c]);
                        xh[c+1] = fmaf(bh(v[j]), wp[c+1], xh[c+1]);
                    }
                }
            }
        }
        #pragma unroll
        for (int g = 0; g < 8; ++g) {
            f4v q = (f4v){xh[4*g], xh[4*g+1], xh[4*g+2], xh[4*g+3]};
            q = gelu4(q);
            xh[4*g]=q[0]; xh[4*g+1]=q[1]; xh[4*g+2]=q[2]; xh[4*g+3]=q[3];
        }
        WSYNC();
        #pragma unroll
        for (int c8 = 0; c8 < 4; ++c8) {
            u4v w;
            #pragma unroll
            for (int j = 0; j < 4; ++j) w[j] = pk2(xh[c8*8+2*j], xh[c8*8+2*j+1]);
            *(u4v*)(Wp + t*72 + h*32 + c8*8) = w;
        }
    }
    WSYNC();

    // ---------------- P4.5: channel mean (lane = channel) + proj GEMM ----------------
    float pc;
    {
        float ps = 0.f;
        #pragma unroll 1
        for (int p8 = 0; p8 < 8; ++p8) {
            #pragma unroll
            for (int q = 0; q < 8; ++q) ps += bl((uint32)Wp[(p8*8+q)*72 + t]);
        }
        pc = ps * (1.f/64.f);
    }
    f4v accp[4][2];
    #pragma unroll
    for (int m = 0; m < 4; ++m) { accp[m][0] = (f4v){0.f,0.f,0.f,0.f}; accp[m][1] = (f4v){0.f,0.f,0.f,0.f}; }
    {
        bf8v a0[4], a1[4];
        #pragma unroll
        for (int m = 0; m < 4; ++m) a0[m] = *(const bf8v*)(Wp + (m*16 + l4)*72 + g4*8);
        #pragma unroll
        for (int m = 0; m < 4; ++m) a1[m] = *(const bf8v*)(Wp + (m*16 + l4)*72 + 32 + g4*8);
        #pragma unroll
        for (int m = 0; m < 4; ++m)
            #pragma unroll
            for (int n = 0; n < 2; ++n)
                accp[m][n] = __builtin_amdgcn_mfma_f32_16x16x32_bf16(a0[m], projW[n], accp[m][n], 0,0,0);
        #pragma unroll
        for (int m = 0; m < 4; ++m)
            #pragma unroll
            for (int n = 0; n < 2; ++n)
                accp[m][n] = __builtin_amdgcn_mfma_f32_16x16x32_bf16(a1[m], projW[2+n], accp[m][n], 0,0,0);
    }
    {
        float bp0 = proj_b[l4], bp1 = proj_b[16 + l4];
        #pragma unroll
        for (int m = 0; m < 4; ++m)
            #pragma unroll
            for (int r = 0; r < 4; ++r) { accp[m][0][r] += bp0; accp[m][1][r] += bp1; }
    }
    // prefetch dwb_w0 weights (consumed in P7, after the long P5 phase)
    bf8v dwb0W[2];
    #pragma unroll
    for (int n = 0; n < 2; ++n)
        dwb0W[n] = *(const bf8v*)(wsw + W_DWB0_OFF + (n*16+l4)*32 + g4*8);
    WSYNC();
    #pragma unroll
    for (int m = 0; m < 4; ++m)
        #pragma unroll
        for (int n = 0; n < 2; ++n)
            #pragma unroll
            for (int r = 0; r < 4; ++r)
                Wp[(m*16 + g4*4 + r)*72 + n*16 + l4] = bfr(accp[m][n][r]);
    WSYNC();
    uint32 xppk[16];
    #pragma unroll
    for (int q8 = 0; q8 < 4; ++q8) {
        u4v v = *(const u4v*)(Wp + t*72 + q8*8);
        #pragma unroll
        for (int j = 0; j < 4; ++j) xppk[q8*4 + j] = v[j];
    }

    // ---------------- P5: SE gate (distributed matvec via shfl butterfly) ----------------
    {
        float pt[8];
        {
            f4v wa = *(const f4v*)(wf + F_CI1T + t*8);
            f4v wb = *(const f4v*)(wf + F_CI1T + t*8 + 4);
            #pragma unroll
            for (int m = 0; m < 4; ++m) { pt[m] = wa[m]*pc; pt[4+m] = wb[m]*pc; }
        }
        #pragma unroll
        for (int st = 1; st < 64; st <<= 1)
            #pragma unroll
            for (int m = 0; m < 8; ++m) pt[m] += __shfl_xor(pt[m], st, 64);
        float t8[8];
        #pragma unroll
        for (int m = 0; m < 8; ++m) t8[m] = pt[m] + ci_b1[m];
        float s = 0.f;
        #pragma unroll
        for (int m = 0; m < 8; ++m) s += t8[m];
        float mu = s * 0.125f;
        float q2 = 0.f;
        #pragma unroll
        for (int m = 0; m < 8; ++m) { float d = t8[m]-mu; q2 = fmaf(d,d,q2); }
        float rstd = rsqrtf(q2*0.125f + EPSF);
        #pragma unroll
        for (int m = 0; m < 8; ++m) t8[m] = (t8[m]-mu)*rstd*ci_ln_w[m] + ci_ln_b[m];
        f4v qa = gelu4((f4v){t8[0],t8[1],t8[2],t8[3]});
        f4v qb = gelu4((f4v){t8[4],t8[5],t8[6],t8[7]});
        t8[0]=qa[0]; t8[1]=qa[1]; t8[2]=qa[2]; t8[3]=qa[3];
        t8[4]=qb[0]; t8[5]=qb[1]; t8[6]=qb[2]; t8[7]=qb[3];
        if (t < 32) {
            float a = ci_b2[t];
            #pragma unroll
            for (int m = 0; m < 8; ++m) a = fmaf(wf[F_CI2T + m*32 + t], t8[m], a);
            segate_s[wid][t] = sigm(a);
        }
    }
    WSYNC();
    float sg[32];
    #pragma unroll
    for (int g = 0; g < 8; ++g) {
        f4v e = *(const f4v*)&segate_s[wid][g*4];
        #pragma unroll
        for (int r = 0; r < 4; ++r) {
            int o = g*4 + r;
            uint32 pkv = hidpk[16 + o/2];
            float gv = (o & 1) ? bh(pkv) : bl(pkv);
            sg[o] = gv * e[r];
        }
    }
    {   // SGU LayerNorm over 32
        float s = 0.f;
        #pragma unroll
        for (int o = 0; o < 32; ++o) s += sg[o];
        float mu = s * (1.f/32.f);
        float q2 = 0.f;
        #pragma unroll
        for (int o = 0; o < 32; ++o) { float d = sg[o]-mu; q2 = fmaf(d,d,q2); }
        float rstd = rsqrtf(q2*(1.f/32.f) + EPSF);
        #pragma unroll
        for (int o = 0; o < 32; ++o) sg[o] = (sg[o]-mu)*rstd*sgu_ln_w[o] + sgu_ln_b[o];
    }
    WSYNC();
    #pragma unroll
    for (int c8 = 0; c8 < 4; ++c8) {
        u4v w;
        #pragma unroll
        for (int j = 0; j < 4; ++j) w[j] = pk2(sg[c8*8+2*j], sg[c8*8+2*j+1]);
        *(u4v*)(Wp + t*72 + c8*8) = w;
    }
    WSYNC();

    // ---------------- P7: dwb_w0 GEMM -> write g1 TRANSPOSED (Gt, cols 32..63) ----------------
    bf8v dwb2W[2];
    {
        f4v accg[4][2];
        #pragma unroll
        for (int m = 0; m < 4; ++m) { accg[m][0] = (f4v){0.f,0.f,0.f,0.f}; accg[m][1] = (f4v){0.f,0.f,0.f,0.f}; }
        bf8v av[4];
        #pragma unroll
        for (int m = 0; m < 4; ++m) av[m] = *(const bf8v*)(Wp + (m*16 + l4)*72 + g4*8);
        #pragma unroll
        for (int m = 0; m < 4; ++m)
            #pragma unroll
            for (int n = 0; n < 2; ++n)
                accg[m][n] = __builtin_amdgcn_mfma_f32_16x16x32_bf16(av[m], dwb0W[n], accg[m][n], 0,0,0);
        // prefetch dwb_w2 weights (consumed in P9, after the long P8 phase)
        #pragma unroll
        for (int n = 0; n < 2; ++n)
            dwb2W[n] = *(const bf8v*)(wsw + W_DWB2_OFF + (n*16+l4)*32 + g4*8);
        WSYNC();
        #pragma unroll
        for (int m = 0; m < 4; ++m)
            #pragma unroll
            for (int n = 0; n < 2; ++n)
                #pragma unroll
                for (int r = 0; r < 4; ++r) {
                    int q = m*16 + g4*4 + r;
                    Wp[((q>>5)*32 + n*16 + l4)*72 + 32 + (q & 31)] = bfr(accg[m][n][r]);
                }
    }
    WSYNC();

    // ---------------- P8: idw kernel gen + dynamic 7x7 via MFMA (K-split M build) ----------------
    float t8b[8];
    #pragma unroll
    for (int m = 0; m < 8; ++m) t8b[m] = idw_b1[m];
    #pragma unroll 1
    for (int c = 0; c < 32; ++c) {      // g1 row t = Gt column t
        float gv = bl((uint32)Wp[((t>>5)*32 + c)*72 + 32 + (t & 31)]);
        #pragma unroll
        for (int m = 0; m < 8; ++m) t8b[m] = fmaf(wf[F_IW1T + c*8 + m], gv, t8b[m]);
    }
    #pragma unroll
    for (int m = 0; m < 8; ++m)
        t8b[m] = fmaxf(t8b[m]*(idw_bn_w[m]*0.9999950000374997f) + idw_bn_b[m], 0.f);

    f4v accd[4][2];
    #pragma unroll
    for (int m = 0; m < 4; ++m) { accd[m][0] = (f4v){0.f,0.f,0.f,0.f}; accd[m][1] = (f4v){0.f,0.f,0.f,0.f}; }
    #pragma unroll 1
    for (int s = 0; s < 2; ++s) {
        WSYNC();
        #pragma unroll
        for (int i = 0; i < 4; ++i) *(u4v*)(Wp + t*72 + i*8) = (u4v){0,0,0,0};
        #pragma unroll 1
        for (int ki = 0; ki < 7; ++ki) {
            int rr = py + ki - 3;
            #pragma unroll 1
            for (int kj = 0; kj < 7; ++kj) {
                int cc = px + kj - 3;
                int k  = ki*7 + kj;
                float wk = idw_b2[k];
                #pragma unroll
                for (int m = 0; m < 8; ++m) wk = fmaf(idw_w2[k*8 + m], t8b[m], wk);
                int q = rr*8 + cc;
                if (((unsigned)rr < 8u) && ((unsigned)cc < 8u) && ((q >> 5) == s))
                    Wp[t*72 + (q & 31)] = bfr(wk);
            }
        }
        WSYNC();
        bf8v aM[4], bG[2];
        #pragma unroll
        for (int m = 0; m < 4; ++m) aM[m] = *(const bf8v*)(Wp + (m*16 + l4)*72 + g4*8);
        #pragma unroll
        for (int n = 0; n < 2; ++n) bG[n] = *(const bf8v*)(Wp + (s*32 + n*16 + l4)*72 + 32 + g4*8);
        #pragma unroll
        for (int m = 0; m < 4; ++m)
            #pragma unroll
            for (int n = 0; n < 2; ++n)
                accd[m][n] = __builtin_amdgcn_mfma_f32_16x16x32_bf16(aM[m], bG[n], accd[m][n], 0,0,0);
    }
    WSYNC();
    #pragma unroll
    for (int m = 0; m < 4; ++m)
        #pragma unroll
        for (int n = 0; n < 2; ++n)
            #pragma unroll
            for (int r = 0; r < 4; ++r)
                Wp[(m*16 + g4*4 + r)*72 + n*16 + l4] = bfr(accd[m][n][r]);
    WSYNC();

    // ---------------- P9: dwb_w2 GEMM -> sgu = g2 * res ----------------
    bf8v outW[8];
    {
        f4v accg[4][2];
        #pragma unroll
        for (int m = 0; m < 4; ++m) { accg[m][0] = (f4v){0.f,0.f,0.f,0.f}; accg[m][1] = (f4v){0.f,0.f,0.f,0.f}; }
        bf8v av[4];
        #pragma unroll
        for (int m = 0; m < 4; ++m) av[m] = *(const bf8v*)(Wp + (m*16 + l4)*72 + g4*8);
        #pragma unroll
        for (int m = 0; m < 4; ++m)
            #pragma unroll
            for (int n = 0; n < 2; ++n)
                accg[m][n] = __builtin_amdgcn_mfma_f32_16x16x32_bf16(av[m], dwb2W[n], accg[m][n], 0,0,0);
        // prefetch out weights (consumed in P11, after the P10 phase)
        #pragma unroll
        for (int s = 0; s < 2; ++s)
            #pragma unroll
            for (int n = 0; n < 4; ++n)
                outW[s*4+n] = *(const bf8v*)(wsw + W_OUT_OFF + (n*16+l4)*64 + s*32 + g4*8);
        WSYNC();
        #pragma unroll
        for (int m = 0; m < 4; ++m)
            #pragma unroll
            for (int n = 0; n < 2; ++n)
                #pragma unroll
                for (int r = 0; r < 4; ++r)
                    Wp[(m*16 + g4*4 + r)*72 + n*16 + l4] = bfr(accg[m][n][r]);
        WSYNC();
    }
    float sgu[32];
    #pragma unroll
    for (int q8 = 0; q8 < 4; ++q8) {
        u4v v = *(const u4v*)(Wp + t*72 + q8*8);
        #pragma unroll
        for (int j = 0; j < 4; ++j) {
            int q = q8*4 + j;
            sgu[2*q]   = bl(v[j]) * bl(hidpk[q]);
            sgu[2*q+1] = bh(v[j]) * bh(hidpk[q]);
        }
    }
    WSYNC();

    // ---------------- P10: stage sgu (cols 32..63), si gate, stage xp*siv ----------------
    #pragma unroll
    for (int c8 = 0; c8 < 4; ++c8) {
        u4v w;
        #pragma unroll
        for (int j = 0; j < 4; ++j) w[j] = pk2(sgu[c8*8+2*j], sgu[c8*8+2*j+1]);
        *(u4v*)(Wp + t*72 + 32 + c8*8) = w;
    }
    WSYNC();
    float siv;
    {
        float s1[4];
        #pragma unroll
        for (int m = 0; m < 4; ++m) s1[m] = si_b1[m];
        #pragma unroll 1
        for (int c8 = 0; c8 < 4; ++c8) {
            u4v v = *(const u4v*)(Wp + t*72 + 32 + c8*8);
            #pragma unroll
            for (int j = 0; j < 4; ++j) {
                int c = c8*8 + 2*j;
                float a0 = bl(v[j]), a1 = bh(v[j]);
                #pragma unroll
                for (int m = 0; m < 4; ++m) {
                    s1[m] = fmaf(wf[F_SI1T + c*4 + m],     a0, s1[m]);
                    s1[m] = fmaf(wf[F_SI1T + (c+1)*4 + m], a1, s1[m]);
                }
            }
        }
        float s = s1[0]+s1[1]+s1[2]+s1[3];
        float mu = s * 0.25f;
        float q2 = 0.f;
        #pragma unroll
        for (int m = 0; m < 4; ++m) { float d = s1[m]-mu; q2 = fmaf(d,d,q2); }
        float rstd = rsqrtf(q2*0.25f + EPSF);
        f4v q;
        #pragma unroll
        for (int m = 0; m < 4; ++m) q[m] = (s1[m]-mu)*rstd*si_ln_w[m] + si_ln_b[m];
        q = gelu4(q);
        float a = si_b2[0];
        #pragma unroll
        for (int m = 0; m < 4; ++m) a = fmaf(si_w2[m], q[m], a);
        siv = sigm(a);
    }
    #pragma unroll
    for (int c8 = 0; c8 < 4; ++c8) {
        u4v w;
        #pragma unroll
        for (int j = 0; j < 4; ++j) {
            int q = c8*4 + j;
            w[j] = pk2(bl(xppk[q])*siv, bh(xppk[q])*siv);
        }
        *(u4v*)(Wp + t*72 + c8*8) = w;
    }
    WSYNC();

    // ---------------- P11: out GEMM + bias ----------------
    #pragma unroll
    for (int m = 0; m < 4; ++m)
        #pragma unroll
        for (int n = 0; n < 4; ++n)
            acc[m][n] = (f4v){0.f,0.f,0.f,0.f};
    {
        bf8v a0[4], a1[4];
        #pragma unroll
        for (int m = 0; m < 4; ++m) a0[m] = *(const bf8v*)(Wp + (m*16 + l4)*72 + g4*8);
        #pragma unroll
        for (int m = 0; m < 4; ++m) a1[m] = *(const bf8v*)(Wp + (m*16 + l4)*72 + 32 + g4*8);
        #pragma unroll
        for (int m = 0; m < 4; ++m)
            #pragma unroll
            for (int n = 0; n < 4; ++n)
                acc[m][n] = __builtin_amdgcn_mfma_f32_16x16x32_bf16(a0[m], outW[n], acc[m][n], 0,0,0);
        #pragma unroll
        for (int m = 0; m < 4; ++m)
            #pragma unroll
            for (int n = 0; n < 4; ++n)
                acc[m][n] = __builtin_amdgcn_mfma_f32_16x16x32_bf16(a1[m], outW[4+n], acc[m][n], 0,0,0);
    }
    {
        float bo[4];
        #pragma unroll
        for (int n = 0; n < 4; ++n) bo[n] = out_b[n*16 + l4];
        #pragma unroll
        for (int m = 0; m < 4; ++m)
            #pragma unroll
            for (int n = 0; n < 4; ++n)
                #pragma unroll
                for (int r = 0; r < 4; ++r)
                    acc[m][n][r] += bo[n];
    }
    WSYNC();
    #pragma unroll
    for (int m = 0; m < 4; ++m)
        #pragma unroll
        for (int n = 0; n < 4; ++n)
            #pragma unroll
            for (int r = 0; r < 4; ++r)
                Wp[(m*16 + g4*4 + r)*72 + n*16 + l4] = bfr(acc[m][n][r]);
    __syncthreads();

    // ---------------- P12: cooperative coalesced store (nontemporal) ----------------
    {
        float* obase = out + (bb*64)*HWSZ + (ph*8)*256 + strip*32;
        const unsigned short* lsrc = bufS + lp*PSTR + (ty*8 + lpx)*72;
        #pragma unroll 1
        for (int c8 = 0; c8 < 8; ++c8) {
            u4v v = *(const u4v*)(lsrc + c8*8);
            #pragma unroll
            for (int j = 0; j < 4; ++j) {
                int c = c8*8 + 2*j;
                __builtin_nontemporal_store(bl(v[j]), obase + c*HWSZ + yx);
                __builtin_nontemporal_store(bh(v[j]), obase + (c+1)*HWSZ + yx);
            }
        }
    }
}

extern "C" void kernel_launch(void* const* d_in, const int* in_sizes, int n_in,
                              void* d_out, int out_size, void* d_ws, size_t ws_size,
                              hipStream_t stream) {
    const float* p[35];
    for (int i = 0; i < 35; ++i) p[i] = (const float*)d_in[i];
    unsigned short* ws = (unsigned short*)d_ws;
    float* wsf = (float*)ws + 8192;

    prep_w<<<64, 256, 0, stream>>>(p[1], p[3], p[21], p[23], p[27], p[34], ws);
    prep_t<<<7, 256, 0, stream>>>(p[7], p[9], p[13], p[28], p[15], wsf);

    const int B = in_sizes[0] / (64 * 256 * 256);   // = 4
    dim3 grid(B * 32 * 8), block(256);
    gmlp_fused<<<grid, block, 0, stream>>>(
        p[0],  p[2],  p[4],  p[5],  p[6],  p[8],
        p[10], p[11], p[12], p[14],
        p[16], p[17], p[18], p[19], p[20],
        p[22], p[24], p[25], p[26],
        p[29], p[30], p[31], p[32], p[33],
        ws, (float*)d_out);
}